// Round 3
// baseline (4596.390 us; speedup 1.0000x reference)
//
#include <hip/hip_runtime.h>
#include <hip/hip_bf16.h>
#include <math.h>

typedef __hip_bfloat16 bf16;
typedef __attribute__((ext_vector_type(8))) short bf16x8;
typedef __attribute__((ext_vector_type(4))) float f32x4;

#define EPI_BF16 0
#define EPI_BIAS_BF16 1
#define EPI_BIAS_GELU_BF16 2
#define EPI_BIAS_F32 3
#define EPI_SCALE_BF16 4

__device__ __forceinline__ float gelu_tanh(float x) {
  const float c = 0.7978845608028654f;
  float t = tanhf(c * (x + 0.044715f * x * x * x));
  return 0.5f * x * (1.0f + t);
}

// C = A @ Bt^T (+bias, epilogue). A:[M][K] bf16 lda, Bt:[N][K] bf16 ldb, batched over z.
// BM=128 fixed, BN in {128,64}. 256 threads = 4 waves, wave tile 64 x BN/2.
// Staging: register-routed (global int4 -> VGPR -> ds_write_b128).
template<int BN, int EPI, typename CT>
__global__ __launch_bounds__(256) void gemm_bt(
    const bf16* __restrict__ A, long sAz, int lda,
    const bf16* __restrict__ Bt, long sBz, int ldb,
    CT* __restrict__ C, long sCz, int ldc,
    const float* __restrict__ bias,
    int K, float scale)
{
  constexpr int BM = 128, BK = 32;
  constexpr int WN = BN / 2, NJ = WN / 16;
  constexpr int NB = BN / 64;
  __shared__ __align__(16) bf16 As[BM * BK];
  __shared__ __align__(16) bf16 Bs[BN * BK];
  const int t = threadIdx.x;
  const int lane = t & 63, w = t >> 6;
  const int wm = (w >> 1) * 64, wn = (w & 1) * WN;
  const long z = blockIdx.z;
  const bf16* Ab = A + z * sAz + (long)blockIdx.y * BM * lda;
  const bf16* Bb = Bt + z * sBz + (long)blockIdx.x * BN * ldb;

  f32x4 acc[4][NJ];
  #pragma unroll
  for (int i = 0; i < 4; ++i)
    #pragma unroll
    for (int j = 0; j < NJ; ++j)
      acc[i][j] = (f32x4){0.f, 0.f, 0.f, 0.f};

  const int quad = lane >> 4, r16 = lane & 15;

  for (int k0 = 0; k0 < K; k0 += BK) {
    // global -> registers (issued before the barrier for overlap)
    int4 ra[2], rb[NB];
    #pragma unroll
    for (int is = 0; is < 2; ++is) {
      int Lb = is * 4096 + t * 16;          // byte offset in As
      int row = Lb >> 6;                    // 64 B per LDS row (32 bf16)
      int cole = (Lb & 63) >> 1;            // element col within tile
      ra[is] = *(const int4*)((const char*)Ab + (long)row * (lda * 2) + (long)(k0 + cole) * 2);
    }
    #pragma unroll
    for (int is = 0; is < NB; ++is) {
      int Lb = is * 4096 + t * 16;
      int row = Lb >> 6;
      int cole = (Lb & 63) >> 1;
      rb[is] = *(const int4*)((const char*)Bb + (long)row * (ldb * 2) + (long)(k0 + cole) * 2);
    }
    __syncthreads();   // previous iteration's ds_reads complete
    #pragma unroll
    for (int is = 0; is < 2; ++is)
      *(int4*)((char*)As + is * 4096 + t * 16) = ra[is];
    #pragma unroll
    for (int is = 0; is < NB; ++is)
      *(int4*)((char*)Bs + is * 4096 + t * 16) = rb[is];
    __syncthreads();

    bf16x8 af[4], bfv[NJ];
    #pragma unroll
    for (int i = 0; i < 4; ++i)
      af[i] = *(const bf16x8*)&As[(wm + i * 16 + r16) * BK + quad * 8];
    #pragma unroll
    for (int j = 0; j < NJ; ++j)
      bfv[j] = *(const bf16x8*)&Bs[(wn + j * 16 + r16) * BK + quad * 8];
    #pragma unroll
    for (int i = 0; i < 4; ++i)
      #pragma unroll
      for (int j = 0; j < NJ; ++j)
        acc[i][j] = __builtin_amdgcn_mfma_f32_16x16x32_bf16(af[i], bfv[j], acc[i][j], 0, 0, 0);
  }

  // epilogue: within a 16x16 tile, col = lane&15, row = (lane>>4)*4 + r  (m89/m91)
  CT* Cb = C + z * sCz;
  #pragma unroll
  for (int i = 0; i < 4; ++i) {
    #pragma unroll
    for (int j = 0; j < NJ; ++j) {
      int col = blockIdx.x * BN + wn + j * 16 + r16;
      float bvv = 0.f;
      if constexpr (EPI == EPI_BIAS_BF16 || EPI == EPI_BIAS_GELU_BF16 || EPI == EPI_BIAS_F32)
        bvv = bias[col];
      #pragma unroll
      for (int r = 0; r < 4; ++r) {
        long row = (long)blockIdx.y * BM + wm + i * 16 + quad * 4 + r;
        float val = acc[i][j][r] * scale + bvv;
        if constexpr (EPI == EPI_BIAS_GELU_BF16) val = gelu_tanh(val);
        if constexpr (sizeof(CT) == 2)
          Cb[row * (long)ldc + col] = __float2bfloat16(val);
        else
          Cb[row * (long)ldc + col] = val;
      }
    }
  }
}

// fp32 weight [R][C] -> bf16 transposed [C][R]
__global__ __launch_bounds__(256) void transpose_cast(
    const float* __restrict__ in, bf16* __restrict__ out, int R, int C)
{
  __shared__ bf16 tile[32][33];
  const int tx = threadIdx.x, ty = threadIdx.y;
  const int r0 = blockIdx.y * 32, c0 = blockIdx.x * 32;
  #pragma unroll
  for (int d = 0; d < 32; d += 8)
    tile[ty + d][tx] = __float2bfloat16(in[(long)(r0 + ty + d) * C + c0 + tx]);
  __syncthreads();
  #pragma unroll
  for (int d = 0; d < 32; d += 8)
    out[(long)(c0 + ty + d) * R + r0 + tx] = tile[tx][ty + d];
}

// bf16 [R][C] -> bf16 transposed [C][R]
__global__ __launch_bounds__(256) void transpose_bf16(
    const bf16* __restrict__ in, bf16* __restrict__ out, int R, int C)
{
  __shared__ bf16 tile[32][33];
  const int tx = threadIdx.x, ty = threadIdx.y;
  const int r0 = blockIdx.y * 32, c0 = blockIdx.x * 32;
  #pragma unroll
  for (int d = 0; d < 32; d += 8)
    tile[ty + d][tx] = in[(long)(r0 + ty + d) * C + c0 + tx];
  __syncthreads();
  #pragma unroll
  for (int d = 0; d < 32; d += 8)
    out[(long)(c0 + ty + d) * R + r0 + tx] = tile[tx][ty + d];
}

__device__ __forceinline__ float blk_sum(float v, float* sh) {
  #pragma unroll
  for (int o = 32; o > 0; o >>= 1) v += __shfl_down(v, o);
  __syncthreads();
  if ((threadIdx.x & 63) == 0) sh[threadIdx.x >> 6] = v;
  __syncthreads();
  return sh[0] + sh[1] + sh[2] + sh[3];
}

__device__ __forceinline__ float blk_max(float v, float* sh) {
  #pragma unroll
  for (int o = 32; o > 0; o >>= 1) v = fmaxf(v, __shfl_down(v, o));
  __syncthreads();
  if ((threadIdx.x & 63) == 0) sh[threadIdx.x >> 6] = v;
  __syncthreads();
  return fmaxf(fmaxf(sh[0], sh[1]), fmaxf(sh[2], sh[3]));
}

// X = LN(X + delta)*g + b (fp32 residual), also writes bf16 copy to xb. Row = 1024 cols.
__global__ __launch_bounds__(256) void ln_residual(
    float* __restrict__ X, const float* __restrict__ delta,
    const float* __restrict__ g, const float* __restrict__ b,
    bf16* __restrict__ xb)
{
  __shared__ float sh[4];
  const int t = threadIdx.x;
  const long base = (long)blockIdx.x * 1024;
  float v[4]; float s = 0.f;
  #pragma unroll
  for (int i = 0; i < 4; ++i) {
    int c = t + i * 256;
    float val = X[base + c] + delta[base + c];
    v[i] = val; s += val;
  }
  s = blk_sum(s, sh);
  const float mu = s * (1.f / 1024.f);
  float s2 = 0.f;
  #pragma unroll
  for (int i = 0; i < 4; ++i) { float d = v[i] - mu; s2 += d * d; }
  s2 = blk_sum(s2, sh);
  const float rs = rsqrtf(s2 * (1.f / 1024.f) + 1e-5f);
  #pragma unroll
  for (int i = 0; i < 4; ++i) {
    int c = t + i * 256;
    float o = (v[i] - mu) * rs * g[c] + b[c];
    X[base + c] = o;
    xb[base + c] = __float2bfloat16(o);
  }
}

// softmax over rows of 2048, in-place bf16. grid (2048 rows, CH heads)
__global__ __launch_bounds__(256) void softmax_rows(bf16* __restrict__ Sc) {
  __shared__ float sh[4];
  const long base = (long)blockIdx.y * (2048L * 2048L) + (long)blockIdx.x * 2048L;
  const int t = threadIdx.x;
  float v[8]; float m = -1e30f;
  #pragma unroll
  for (int i = 0; i < 8; ++i) {
    v[i] = __bfloat162float(Sc[base + t + i * 256]);
    m = fmaxf(m, v[i]);
  }
  m = blk_max(m, sh);
  float s = 0.f;
  #pragma unroll
  for (int i = 0; i < 8; ++i) { v[i] = __expf(v[i] - m); s += v[i]; }
  s = blk_sum(s, sh);
  const float inv = 1.f / s;
  #pragma unroll
  for (int i = 0; i < 8; ++i)
    Sc[base + t + i * 256] = __float2bfloat16(v[i] * inv);
}

__global__ __launch_bounds__(256) void init_x(
    const float* __restrict__ xin, float* __restrict__ X, bf16* __restrict__ xb, int n)
{
  for (int i = blockIdx.x * 256 + threadIdx.x; i < n; i += gridDim.x * 256) {
    float v = xin[i];
    X[i] = v;
    xb[i] = __float2bfloat16(v);
  }
}

__global__ __launch_bounds__(256) void copy_out(
    const float* __restrict__ X, float* __restrict__ out, int n)
{
  for (int i = blockIdx.x * 256 + threadIdx.x; i < n; i += gridDim.x * 256)
    out[i] = X[i];
}

extern "C" void kernel_launch(void* const* d_in, const int* in_sizes, int n_in,
                              void* d_out, int out_size, void* d_ws, size_t ws_size,
                              hipStream_t stream) {
  constexpr int S = 2048, D = 1024, F = 4096, DK = 64, L = 4, CH = 2;
  const float* xin = (const float*)d_in[0];
  const float* wq = (const float*)d_in[1];
  const float* bq = (const float*)d_in[2];
  const float* wk = (const float*)d_in[3];
  const float* bk = (const float*)d_in[4];
  const float* wv = (const float*)d_in[5];
  const float* bvp = (const float*)d_in[6];
  const float* wo = (const float*)d_in[7];
  const float* bo = (const float*)d_in[8];
  const float* w1 = (const float*)d_in[9];
  const float* b1 = (const float*)d_in[10];
  const float* w2 = (const float*)d_in[11];
  const float* b2 = (const float*)d_in[12];
  const float* ln1g = (const float*)d_in[13];
  const float* ln1b = (const float*)d_in[14];
  const float* ln2g = (const float*)d_in[15];
  const float* ln2b = (const float*)d_in[16];

  // workspace layout — 64 MB total (hb overlays dead q/kk/vv/vT during FFN)
  char* p = (char*)d_ws;
  float* X   = (float*)p; p += (long)S * D * 4;   // 8 MB fp32 residual
  float* tmpf= (float*)p; p += (long)S * D * 4;   // 8 MB fp32 pre-LN GEMM out
  bf16* xb   = (bf16*)p;  p += (long)S * D * 2;   // 4 MB bf16 copy of X
  bf16* q    = (bf16*)p;                           // 4 MB
  bf16* hb   = (bf16*)p;  p += (long)S * D * 2;   // FFN intermediate overlays q..vT (16 MB)
  bf16* kk   = (bf16*)p;  p += (long)S * D * 2;
  bf16* vv   = (bf16*)p;  p += (long)S * D * 2;
  bf16* vT   = (bf16*)p;  p += (long)S * D * 2;   // [H][64][S]
  bf16* ctx  = (bf16*)p;  p += (long)S * D * 2;   // 4 MB
  bf16* wT   = (bf16*)p;  p += (long)F * D * 2;   // 8 MB transposed weight scratch
  bf16* sc   = (bf16*)p;  p += (long)CH * S * S * 2; // 16 MB scores, 2 heads/chunk

  init_x<<<2048, 256, 0, stream>>>(xin, X, xb, S * D);

  for (int l = 0; l < L; ++l) {
    const float* pw[3] = {wq + (long)l * D * D, wk + (long)l * D * D, wv + (long)l * D * D};
    const float* pb[3] = {bq + l * D, bk + l * D, bvp + l * D};
    bf16* po[3] = {q, kk, vv};
    for (int pj = 0; pj < 3; ++pj) {
      transpose_cast<<<dim3(D / 32, D / 32), dim3(32, 8), 0, stream>>>(pw[pj], wT, D, D);
      gemm_bt<128, EPI_BIAS_BF16, bf16><<<dim3(D / 128, S / 128, 1), 256, 0, stream>>>(
          xb, 0L, D, wT, 0L, D, po[pj], 0L, D, pb[pj], D, 1.f);
    }
    transpose_bf16<<<dim3(D / 32, S / 32), dim3(32, 8), 0, stream>>>(vv, vT, S, D);
    for (int c = 0; c < 16 / CH; ++c) {
      int h0 = c * CH;
      // scores[z] = (q_h @ k_h^T) / 8, bf16
      gemm_bt<128, EPI_SCALE_BF16, bf16><<<dim3(S / 128, S / 128, CH), 256, 0, stream>>>(
          q + h0 * DK, (long)DK, D, kk + h0 * DK, (long)DK, D,
          sc, (long)S * S, S, nullptr, DK, 0.125f);
      softmax_rows<<<dim3(S, CH), 256, 0, stream>>>(sc);
      // ctx_h = attn @ v_h  (Bt = vT[h] : [64][S])
      gemm_bt<64, EPI_BF16, bf16><<<dim3(1, S / 128, CH), 256, 0, stream>>>(
          sc, (long)S * S, S, vT + (long)h0 * DK * S, (long)DK * S, S,
          ctx + h0 * DK, (long)DK, D, nullptr, S, 1.f);
    }
    transpose_cast<<<dim3(D / 32, D / 32), dim3(32, 8), 0, stream>>>(wo + (long)l * D * D, wT, D, D);
    gemm_bt<128, EPI_BIAS_F32, float><<<dim3(D / 128, S / 128, 1), 256, 0, stream>>>(
        ctx, 0L, D, wT, 0L, D, tmpf, 0L, D, bo + l * D, D, 1.f);
    ln_residual<<<S, 256, 0, stream>>>(X, tmpf, ln1g + l * D, ln1b + l * D, xb);

    transpose_cast<<<dim3(F / 32, D / 32), dim3(32, 8), 0, stream>>>(w1 + (long)l * D * F, wT, D, F);
    gemm_bt<128, EPI_BIAS_GELU_BF16, bf16><<<dim3(F / 128, S / 128, 1), 256, 0, stream>>>(
        xb, 0L, D, wT, 0L, D, hb, 0L, F, b1 + l * F, D, 1.f);
    transpose_cast<<<dim3(D / 32, F / 32), dim3(32, 8), 0, stream>>>(w2 + (long)l * F * D, wT, F, D);
    gemm_bt<128, EPI_BIAS_F32, float><<<dim3(D / 128, S / 128, 1), 256, 0, stream>>>(
        hb, 0L, F, wT, 0L, F, tmpf, 0L, D, b2 + l * D, F, 1.f);
    ln_residual<<<S, 256, 0, stream>>>(X, tmpf, ln2g + l * D, ln2b + l * D, xb);
  }
  copy_out<<<2048, 256, 0, stream>>>(X, (float*)d_out, S * D);
}

// Round 4
// 3480.394 us; speedup vs baseline: 1.3207x; 1.3207x over previous
//
#include <hip/hip_runtime.h>
#include <hip/hip_bf16.h>
#include <math.h>

typedef __hip_bfloat16 bf16;
typedef __attribute__((ext_vector_type(8))) short bf16x8;
typedef __attribute__((ext_vector_type(4))) float f32x4;

#define EPI_BF16 0
#define EPI_BIAS_BF16 1
#define EPI_BIAS_GELU_BF16 2
#define EPI_BIAS_F32 3
#define EPI_SCALE_BF16 4

__device__ __forceinline__ float gelu_tanh(float x) {
  const float c = 0.7978845608028654f;
  float t = tanhf(c * (x + 0.044715f * x * x * x));
  return 0.5f * x * (1.0f + t);
}

// C = A @ Bt^T (+bias, epilogue). A:[M][K] bf16 lda, Bt:[N][K] bf16 ldb, batched over z.
// 256 threads = 4 waves in 2x2 grid; wave tile (BM/2)x(BN/2).
// K-loop software-pipelined: next iteration's global loads prefetched into
// registers while current iteration's MFMAs run.
template<int BM, int BN, int EPI, typename CT>
__global__ __launch_bounds__(256) void gemm_bt(
    const bf16* __restrict__ A, long sAz, int lda,
    const bf16* __restrict__ Bt, long sBz, int ldb,
    CT* __restrict__ C, long sCz, int ldc,
    const float* __restrict__ bias,
    int K, float scale)
{
  constexpr int BK = 32;
  constexpr int WM = BM / 2, WN = BN / 2;
  constexpr int MI = WM / 16, NJ = WN / 16;
  constexpr int NA = (BM * BK * 2) / 4096;   // 16B slices per thread for A
  constexpr int NB = (BN * BK * 2) / 4096;
  __shared__ __align__(16) bf16 As[BM * BK];
  __shared__ __align__(16) bf16 Bs[BN * BK];
  const int t = threadIdx.x;
  const int lane = t & 63, w = t >> 6;
  const int wm = (w >> 1) * WM, wn = (w & 1) * WN;
  const int quad = lane >> 4, r16 = lane & 15;
  const long z = blockIdx.z;
  const bf16* Ab = A + z * sAz + (long)blockIdx.y * BM * lda;
  const bf16* Bb = Bt + z * sBz + (long)blockIdx.x * BN * ldb;

  // per-thread staging source pointers (k0 = 0)
  const char* pa[NA];
  const char* pb[NB];
  #pragma unroll
  for (int s = 0; s < NA; ++s) {
    int Lb = s * 4096 + t * 16;
    int row = Lb >> 6, cole = (Lb & 63) >> 1;   // 64 B per LDS row (32 bf16)
    pa[s] = (const char*)Ab + (long)row * (lda * 2) + cole * 2;
  }
  #pragma unroll
  for (int s = 0; s < NB; ++s) {
    int Lb = s * 4096 + t * 16;
    int row = Lb >> 6, cole = (Lb & 63) >> 1;
    pb[s] = (const char*)Bb + (long)row * (ldb * 2) + cole * 2;
  }

  // preload k0 = 0
  int4 ra[NA], rb[NB];
  #pragma unroll
  for (int s = 0; s < NA; ++s) ra[s] = *(const int4*)(pa[s]);
  #pragma unroll
  for (int s = 0; s < NB; ++s) rb[s] = *(const int4*)(pb[s]);

  f32x4 acc[MI][NJ];
  #pragma unroll
  for (int i = 0; i < MI; ++i)
    #pragma unroll
    for (int j = 0; j < NJ; ++j)
      acc[i][j] = (f32x4){0.f, 0.f, 0.f, 0.f};

  for (int k0 = 0; k0 < K; k0 += BK) {
    __syncthreads();   // previous iteration's ds_reads complete
    #pragma unroll
    for (int s = 0; s < NA; ++s)
      *(int4*)((char*)As + s * 4096 + t * 16) = ra[s];
    #pragma unroll
    for (int s = 0; s < NB; ++s)
      *(int4*)((char*)Bs + s * 4096 + t * 16) = rb[s];
    __syncthreads();

    // prefetch next tile while this tile computes
    if (k0 + BK < K) {
      #pragma unroll
      for (int s = 0; s < NA; ++s) ra[s] = *(const int4*)(pa[s] + (long)(k0 + BK) * 2);
      #pragma unroll
      for (int s = 0; s < NB; ++s) rb[s] = *(const int4*)(pb[s] + (long)(k0 + BK) * 2);
    }

    bf16x8 af[MI], bfv[NJ];
    #pragma unroll
    for (int i = 0; i < MI; ++i)
      af[i] = *(const bf16x8*)&As[(wm + i * 16 + r16) * BK + quad * 8];
    #pragma unroll
    for (int j = 0; j < NJ; ++j)
      bfv[j] = *(const bf16x8*)&Bs[(wn + j * 16 + r16) * BK + quad * 8];
    #pragma unroll
    for (int i = 0; i < MI; ++i)
      #pragma unroll
      for (int j = 0; j < NJ; ++j)
        acc[i][j] = __builtin_amdgcn_mfma_f32_16x16x32_bf16(af[i], bfv[j], acc[i][j], 0, 0, 0);
  }

  // epilogue: within a 16x16 tile, col = lane&15, row = (lane>>4)*4 + r  (m89/m91)
  CT* Cb = C + z * sCz;
  #pragma unroll
  for (int i = 0; i < MI; ++i) {
    #pragma unroll
    for (int j = 0; j < NJ; ++j) {
      int col = blockIdx.x * BN + wn + j * 16 + r16;
      float bvv = 0.f;
      if constexpr (EPI == EPI_BIAS_BF16 || EPI == EPI_BIAS_GELU_BF16 || EPI == EPI_BIAS_F32)
        bvv = bias[col];
      #pragma unroll
      for (int r = 0; r < 4; ++r) {
        long row = (long)blockIdx.y * BM + wm + i * 16 + quad * 4 + r;
        float val = acc[i][j][r] * scale + bvv;
        if constexpr (EPI == EPI_BIAS_GELU_BF16) val = gelu_tanh(val);
        if constexpr (sizeof(CT) == 2)
          Cb[row * (long)ldc + col] = __float2bfloat16(val);
        else
          Cb[row * (long)ldc + col] = val;
      }
    }
  }
}

// fp32 weight [R][C] -> bf16 transposed [C][R]
__global__ __launch_bounds__(256) void transpose_cast(
    const float* __restrict__ in, bf16* __restrict__ out, int R, int C)
{
  __shared__ bf16 tile[32][33];
  const int tx = threadIdx.x, ty = threadIdx.y;
  const int r0 = blockIdx.y * 32, c0 = blockIdx.x * 32;
  #pragma unroll
  for (int d = 0; d < 32; d += 8)
    tile[ty + d][tx] = __float2bfloat16(in[(long)(r0 + ty + d) * C + c0 + tx]);
  __syncthreads();
  #pragma unroll
  for (int d = 0; d < 32; d += 8)
    out[(long)(c0 + ty + d) * R + r0 + tx] = tile[tx][ty + d];
}

// bf16 [R][C] (row stride ldin) -> bf16 transposed [C][R]
__global__ __launch_bounds__(256) void transpose_bf16(
    const bf16* __restrict__ in, bf16* __restrict__ out, int R, int C, int ldin)
{
  __shared__ bf16 tile[32][33];
  const int tx = threadIdx.x, ty = threadIdx.y;
  const int r0 = blockIdx.y * 32, c0 = blockIdx.x * 32;
  #pragma unroll
  for (int d = 0; d < 32; d += 8)
    tile[ty + d][tx] = in[(long)(r0 + ty + d) * ldin + c0 + tx];
  __syncthreads();
  #pragma unroll
  for (int d = 0; d < 32; d += 8)
    out[(long)(c0 + ty + d) * R + r0 + tx] = tile[tx][ty + d];
}

__device__ __forceinline__ float blk_sum(float v, float* sh) {
  #pragma unroll
  for (int o = 32; o > 0; o >>= 1) v += __shfl_down(v, o);
  __syncthreads();
  if ((threadIdx.x & 63) == 0) sh[threadIdx.x >> 6] = v;
  __syncthreads();
  return sh[0] + sh[1] + sh[2] + sh[3];
}

__device__ __forceinline__ float blk_max(float v, float* sh) {
  #pragma unroll
  for (int o = 32; o > 0; o >>= 1) v = fmaxf(v, __shfl_down(v, o));
  __syncthreads();
  if ((threadIdx.x & 63) == 0) sh[threadIdx.x >> 6] = v;
  __syncthreads();
  return fmaxf(fmaxf(sh[0], sh[1]), fmaxf(sh[2], sh[3]));
}

// X = LN(X + delta)*g + b (fp32 residual), also writes bf16 copy to xb.
__global__ __launch_bounds__(256) void ln_residual(
    float* __restrict__ X, const float* __restrict__ delta,
    const float* __restrict__ g, const float* __restrict__ b,
    bf16* __restrict__ xb)
{
  __shared__ float sh[4];
  const int t = threadIdx.x;
  const long base = (long)blockIdx.x * 1024;
  float v[4]; float s = 0.f;
  #pragma unroll
  for (int i = 0; i < 4; ++i) {
    int c = t + i * 256;
    float val = X[base + c] + delta[base + c];
    v[i] = val; s += val;
  }
  s = blk_sum(s, sh);
  const float mu = s * (1.f / 1024.f);
  float s2 = 0.f;
  #pragma unroll
  for (int i = 0; i < 4; ++i) { float d = v[i] - mu; s2 += d * d; }
  s2 = blk_sum(s2, sh);
  const float rs = rsqrtf(s2 * (1.f / 1024.f) + 1e-5f);
  #pragma unroll
  for (int i = 0; i < 4; ++i) {
    int c = t + i * 256;
    float o = (v[i] - mu) * rs * g[c] + b[c];
    X[base + c] = o;
    xb[base + c] = __float2bfloat16(o);
  }
}

// softmax over rows of 2048, in-place bf16. grid (2048 rows, CH heads)
__global__ __launch_bounds__(256) void softmax_rows(bf16* __restrict__ Sc) {
  __shared__ float sh[4];
  const long base = (long)blockIdx.y * (2048L * 2048L) + (long)blockIdx.x * 2048L;
  const int t = threadIdx.x;
  float v[8]; float m = -1e30f;
  #pragma unroll
  for (int i = 0; i < 8; ++i) {
    v[i] = __bfloat162float(Sc[base + t + i * 256]);
    m = fmaxf(m, v[i]);
  }
  m = blk_max(m, sh);
  float s = 0.f;
  #pragma unroll
  for (int i = 0; i < 8; ++i) { v[i] = __expf(v[i] - m); s += v[i]; }
  s = blk_sum(s, sh);
  const float inv = 1.f / s;
  #pragma unroll
  for (int i = 0; i < 8; ++i)
    Sc[base + t + i * 256] = __float2bfloat16(v[i] * inv);
}

__global__ __launch_bounds__(256) void init_x(
    const float* __restrict__ xin, float* __restrict__ X, bf16* __restrict__ xb, int n)
{
  for (int i = blockIdx.x * 256 + threadIdx.x; i < n; i += gridDim.x * 256) {
    float v = xin[i];
    X[i] = v;
    xb[i] = __float2bfloat16(v);
  }
}

__global__ __launch_bounds__(256) void copy_out(
    const float* __restrict__ X, float* __restrict__ out, int n)
{
  for (int i = blockIdx.x * 256 + threadIdx.x; i < n; i += gridDim.x * 256)
    out[i] = X[i];
}

// bias3[l][j][c] = {bq,bk,bv}[l][c]
__global__ __launch_bounds__(256) void concat_bias(
    const float* __restrict__ bq, const float* __restrict__ bk,
    const float* __restrict__ bv, float* __restrict__ out, int n)
{
  for (int i = blockIdx.x * 256 + threadIdx.x; i < n; i += gridDim.x * 256) {
    int l = i / 3072, r = i % 3072;
    int j = r / 1024, c = r % 1024;
    const float* src = (j == 0) ? bq : (j == 1) ? bk : bv;
    out[i] = src[l * 1024 + c];
  }
}

extern "C" void kernel_launch(void* const* d_in, const int* in_sizes, int n_in,
                              void* d_out, int out_size, void* d_ws, size_t ws_size,
                              hipStream_t stream) {
  constexpr int S = 2048, D = 1024, F = 4096, DK = 64, L = 4, CH = 2;
  const float* xin = (const float*)d_in[0];
  const float* wq = (const float*)d_in[1];
  const float* bq = (const float*)d_in[2];
  const float* wk = (const float*)d_in[3];
  const float* bk = (const float*)d_in[4];
  const float* wv = (const float*)d_in[5];
  const float* bvp = (const float*)d_in[6];
  const float* wo = (const float*)d_in[7];
  const float* bo = (const float*)d_in[8];
  const float* w1 = (const float*)d_in[9];
  const float* b1 = (const float*)d_in[10];
  const float* w2 = (const float*)d_in[11];
  const float* b2 = (const float*)d_in[12];
  const float* ln1g = (const float*)d_in[13];
  const float* ln1b = (const float*)d_in[14];
  const float* ln2g = (const float*)d_in[15];
  const float* ln2b = (const float*)d_in[16];

  // workspace — ~60 MB total (proven <= 64 MB safe). hb overlays sc.
  char* p = (char*)d_ws;
  float* X    = (float*)p; p += (long)S * D * 4;       // 8 MB fp32 residual
  float* tmpf = (float*)p; p += (long)S * D * 4;       // 8 MB fp32 pre-LN GEMM out
  bf16* xb    = (bf16*)p;  p += (long)S * D * 2;       // 4 MB bf16 copy of X
  bf16* qkv   = (bf16*)p;  p += (long)S * 3 * D * 2;   // 12 MB [S][3072]
  bf16* ctx   = (bf16*)p;  p += (long)S * D * 2;       // 4 MB
  bf16* vT    = (bf16*)p;  p += (long)S * D * 2;       // 4 MB [H][64][S]
  bf16* wT    = (bf16*)p;  p += (long)F * D * 2;       // 8 MB transposed weight scratch
  float* bias3= (float*)p; p += (long)L * 3 * D * 4;   // 48 KB
  bf16* sc    = (bf16*)p;                               // 16 MB scores (CH=2)
  bf16* hb    = (bf16*)p;  p += (long)CH * S * S * 2;  // FFN intermediate overlays sc

  init_x<<<2048, 256, 0, stream>>>(xin, X, xb, S * D);
  concat_bias<<<48, 256, 0, stream>>>(bq, bk, bvp, bias3, L * 3 * D);

  for (int l = 0; l < L; ++l) {
    // fused QKV: wT rows [j*1024 .. ) hold w{q,k,v}^T
    transpose_cast<<<dim3(D / 32, D / 32), dim3(32, 8), 0, stream>>>(wq + (long)l * D * D, wT, D, D);
    transpose_cast<<<dim3(D / 32, D / 32), dim3(32, 8), 0, stream>>>(wk + (long)l * D * D, wT + (long)D * D, D, D);
    transpose_cast<<<dim3(D / 32, D / 32), dim3(32, 8), 0, stream>>>(wv + (long)l * D * D, wT + 2L * D * D, D, D);
    gemm_bt<128, 128, EPI_BIAS_BF16, bf16><<<dim3(3 * D / 128, S / 128, 1), 256, 0, stream>>>(
        xb, 0L, D, wT, 0L, D, qkv, 0L, 3 * D, bias3 + l * 3 * D, D, 1.f);

    // vT[h][d][s] from v part of qkv
    transpose_bf16<<<dim3(D / 32, S / 32), dim3(32, 8), 0, stream>>>(qkv + 2 * D, vT, S, D, 3 * D);

    for (int c = 0; c < 16 / CH; ++c) {
      int h0 = c * CH;
      gemm_bt<128, 128, EPI_SCALE_BF16, bf16><<<dim3(S / 128, S / 128, CH), 256, 0, stream>>>(
          qkv + h0 * DK, (long)DK, 3 * D, qkv + D + h0 * DK, (long)DK, 3 * D,
          sc, (long)S * S, S, nullptr, DK, 0.125f);
      softmax_rows<<<dim3(S, CH), 256, 0, stream>>>(sc);
      gemm_bt<128, 64, EPI_BF16, bf16><<<dim3(1, S / 128, CH), 256, 0, stream>>>(
          sc, (long)S * S, S, vT + (long)h0 * DK * S, (long)DK * S, S,
          ctx + h0 * DK, (long)DK, D, nullptr, S, 1.f);
    }
    transpose_cast<<<dim3(D / 32, D / 32), dim3(32, 8), 0, stream>>>(wo + (long)l * D * D, wT, D, D);
    gemm_bt<128, 64, EPI_BIAS_F32, float><<<dim3(D / 64, S / 128, 1), 256, 0, stream>>>(
        ctx, 0L, D, wT, 0L, D, tmpf, 0L, D, bo + l * D, D, 1.f);
    ln_residual<<<S, 256, 0, stream>>>(X, tmpf, ln1g + l * D, ln1b + l * D, xb);

    transpose_cast<<<dim3(F / 32, D / 32), dim3(32, 8), 0, stream>>>(w1 + (long)l * D * F, wT, D, F);
    gemm_bt<128, 128, EPI_BIAS_GELU_BF16, bf16><<<dim3(F / 128, S / 128, 1), 256, 0, stream>>>(
        xb, 0L, D, wT, 0L, D, hb, 0L, F, b1 + l * F, D, 1.f);
    transpose_cast<<<dim3(D / 32, F / 32), dim3(32, 8), 0, stream>>>(w2 + (long)l * F * D, wT, F, D);
    gemm_bt<128, 64, EPI_BIAS_F32, float><<<dim3(D / 64, S / 128, 1), 256, 0, stream>>>(
        hb, 0L, F, wT, 0L, F, tmpf, 0L, D, b2 + l * D, F, 1.f);
    ln_residual<<<S, 256, 0, stream>>>(X, tmpf, ln2g + l * D, ln2b + l * D, xb);
  }
  copy_out<<<2048, 256, 0, stream>>>(X, (float*)d_out, S * D);
}

// Round 5
// 1871.139 us; speedup vs baseline: 2.4565x; 1.8600x over previous
//
#include <hip/hip_runtime.h>
#include <hip/hip_bf16.h>
#include <math.h>

typedef __hip_bfloat16 bf16;
typedef __attribute__((ext_vector_type(8))) short bf16x8;
typedef __attribute__((ext_vector_type(4))) float f32x4;

#define EPI_NONE 0
#define EPI_BIAS_BF16 1
#define EPI_BIAS_GELU_BF16 2

__device__ __forceinline__ float gelu_tanh(float x) {
  const float c = 0.7978845608028654f;
  float t = tanhf(c * (x + 0.044715f * x * x * x));
  return 0.5f * x * (1.0f + t);
}

// C = A @ Bt^T (+bias, epilogue). A:[M][K] bf16 lda, Bt:[N][K] bf16 ldb.
// z dim: generic slab offsets (used for split-K: sAz/sBz shift K-columns,
// sCz selects fp32 partial slab). 256 thr = 4 waves, wave tile (BM/2)x(BN/2).
template<int BM, int BN, int EPI, typename CT>
__global__ __launch_bounds__(256) void gemm_bt(
    const bf16* __restrict__ A, long sAz, int lda,
    const bf16* __restrict__ Bt, long sBz, int ldb,
    CT* __restrict__ C, long sCz, int ldc,
    const float* __restrict__ bias,
    int K, float scale)
{
  constexpr int BK = 32;
  constexpr int WM = BM / 2, WN = BN / 2;
  constexpr int MI = WM / 16, NJ = WN / 16;
  constexpr int NA = (BM * BK * 2) / 4096;
  constexpr int NB = (BN * BK * 2) / 4096;
  __shared__ __align__(16) bf16 As[BM * BK];
  __shared__ __align__(16) bf16 Bs[BN * BK];
  const int t = threadIdx.x;
  const int lane = t & 63, w = t >> 6;
  const int wm = (w >> 1) * WM, wn = (w & 1) * WN;
  const int quad = lane >> 4, r16 = lane & 15;
  const long z = blockIdx.z;
  const bf16* Ab = A + z * sAz + (long)blockIdx.y * BM * lda;
  const bf16* Bb = Bt + z * sBz + (long)blockIdx.x * BN * ldb;

  const char* pa[NA];
  const char* pb[NB];
  #pragma unroll
  for (int s = 0; s < NA; ++s) {
    int Lb = s * 4096 + t * 16;
    int row = Lb >> 6, cole = (Lb & 63) >> 1;
    pa[s] = (const char*)Ab + (long)row * (lda * 2) + cole * 2;
  }
  #pragma unroll
  for (int s = 0; s < NB; ++s) {
    int Lb = s * 4096 + t * 16;
    int row = Lb >> 6, cole = (Lb & 63) >> 1;
    pb[s] = (const char*)Bb + (long)row * (ldb * 2) + cole * 2;
  }

  int4 ra[NA], rb[NB];
  #pragma unroll
  for (int s = 0; s < NA; ++s) ra[s] = *(const int4*)(pa[s]);
  #pragma unroll
  for (int s = 0; s < NB; ++s) rb[s] = *(const int4*)(pb[s]);

  f32x4 acc[MI][NJ];
  #pragma unroll
  for (int i = 0; i < MI; ++i)
    #pragma unroll
    for (int j = 0; j < NJ; ++j)
      acc[i][j] = (f32x4){0.f, 0.f, 0.f, 0.f};

  for (int k0 = 0; k0 < K; k0 += BK) {
    __syncthreads();
    #pragma unroll
    for (int s = 0; s < NA; ++s)
      *(int4*)((char*)As + s * 4096 + t * 16) = ra[s];
    #pragma unroll
    for (int s = 0; s < NB; ++s)
      *(int4*)((char*)Bs + s * 4096 + t * 16) = rb[s];
    __syncthreads();

    if (k0 + BK < K) {
      #pragma unroll
      for (int s = 0; s < NA; ++s) ra[s] = *(const int4*)(pa[s] + (long)(k0 + BK) * 2);
      #pragma unroll
      for (int s = 0; s < NB; ++s) rb[s] = *(const int4*)(pb[s] + (long)(k0 + BK) * 2);
    }

    bf16x8 af[MI], bfv[NJ];
    #pragma unroll
    for (int i = 0; i < MI; ++i)
      af[i] = *(const bf16x8*)&As[(wm + i * 16 + r16) * BK + quad * 8];
    #pragma unroll
    for (int j = 0; j < NJ; ++j)
      bfv[j] = *(const bf16x8*)&Bs[(wn + j * 16 + r16) * BK + quad * 8];
    #pragma unroll
    for (int i = 0; i < MI; ++i)
      #pragma unroll
      for (int j = 0; j < NJ; ++j)
        acc[i][j] = __builtin_amdgcn_mfma_f32_16x16x32_bf16(af[i], bfv[j], acc[i][j], 0, 0, 0);
  }

  CT* Cb = C + z * sCz;
  #pragma unroll
  for (int i = 0; i < MI; ++i) {
    #pragma unroll
    for (int j = 0; j < NJ; ++j) {
      int col = blockIdx.x * BN + wn + j * 16 + r16;
      float bvv = 0.f;
      if constexpr (EPI == EPI_BIAS_BF16 || EPI == EPI_BIAS_GELU_BF16)
        bvv = bias[col];
      #pragma unroll
      for (int r = 0; r < 4; ++r) {
        long row = (long)blockIdx.y * BM + wm + i * 16 + quad * 4 + r;
        float val = acc[i][j][r] * scale + bvv;
        if constexpr (EPI == EPI_BIAS_GELU_BF16) val = gelu_tanh(val);
        if constexpr (sizeof(CT) == 2)
          Cb[row * (long)ldc + col] = __float2bfloat16(val);
        else
          Cb[row * (long)ldc + col] = val;
      }
    }
  }
}

// Fused flash attention: per block = (128-row Q tile, one head).
// qkv:[S][3072] (q|k|v), vT:[H*64][S]. out ctx:[S][1024] bf16.
// K-tiles of 64 keys, online softmax, P through padded LDS (stride 72 elem = 144B).
__global__ __launch_bounds__(256) void flash_attn(
    const bf16* __restrict__ qkv, const bf16* __restrict__ vT,
    bf16* __restrict__ ctx)
{
  constexpr int SEQ = 2048, LDP = 72;
  __shared__ __align__(16) bf16 Qs[128 * 64];
  __shared__ __align__(16) bf16 Ks[64 * LDP];
  __shared__ __align__(16) bf16 VTs[64 * LDP];
  __shared__ __align__(16) bf16 Ps[128 * LDP];

  const int t = threadIdx.x;
  const int lane = t & 63, w = t >> 6;
  const int quad = lane >> 4, r16 = lane & 15;
  const int wq0 = w * 32;                 // wave's 32 Q rows within tile
  const int s0 = blockIdx.x * 128;
  const int h = blockIdx.y;

  // ---- stage Q tile [128][64] (register route, unpadded) ----
  {
    #pragma unroll
    for (int s = 0; s < 4; ++s) {
      int Lb = s * 4096 + t * 16;
      int row = Lb >> 7, colb = Lb & 127;
      int4 v = *(const int4*)(qkv + (long)(s0 + row) * 3072 + h * 64 + (colb >> 1));
      *(int4*)((char*)Qs + Lb) = v;
    }
  }

  // K/V staging pointers (iter k0 added later)
  const bf16* kp[2]; const bf16* vp[2];
  int krow[2], kcolb[2];
  #pragma unroll
  for (int s = 0; s < 2; ++s) {
    int Lb = s * 4096 + t * 16;
    krow[s] = Lb >> 7; kcolb[s] = Lb & 127;
    kp[s] = qkv + 1024 + (long)h * 64 + (long)krow[s] * 3072 + (kcolb[s] >> 1);
    vp[s] = vT + (long)(h * 64 + krow[s]) * SEQ + (kcolb[s] >> 1);
  }

  int4 rk[2], rv[2];
  #pragma unroll
  for (int s = 0; s < 2; ++s) {
    rk[s] = *(const int4*)(kp[s]);
    rv[s] = *(const int4*)(vp[s]);
  }

  __syncthreads();
  // Q fragments (read once; 16-way bank conflict is a one-time ~300cyc cost)
  bf16x8 af_q[2][2];
  #pragma unroll
  for (int i = 0; i < 2; ++i)
    #pragma unroll
    for (int kk = 0; kk < 2; ++kk)
      af_q[i][kk] = *(const bf16x8*)&Qs[(wq0 + i * 16 + r16) * 64 + kk * 32 + quad * 8];

  f32x4 O[2][4];
  float m_s[2][4], l_s[2][4];
  #pragma unroll
  for (int i = 0; i < 2; ++i) {
    #pragma unroll
    for (int jd = 0; jd < 4; ++jd) O[i][jd] = (f32x4){0.f, 0.f, 0.f, 0.f};
    #pragma unroll
    for (int r = 0; r < 4; ++r) { m_s[i][r] = -1e30f; l_s[i][r] = 0.f; }
  }

  for (int kt = 0; kt < SEQ / 64; ++kt) {
    __syncthreads();   // prior iter's Ks/VTs/Ps reads complete
    #pragma unroll
    for (int s = 0; s < 2; ++s) {
      *(int4*)((char*)Ks + (krow[s] * LDP * 2) + kcolb[s]) = rk[s];
      *(int4*)((char*)VTs + (krow[s] * LDP * 2) + kcolb[s]) = rv[s];
    }
    __syncthreads();

    // prefetch next K-tile
    if (kt + 1 < SEQ / 64) {
      long k0n = (long)(kt + 1) * 64;
      #pragma unroll
      for (int s = 0; s < 2; ++s) {
        rk[s] = *(const int4*)(kp[s] + k0n * 3072);
        rv[s] = *(const int4*)(vp[s] + k0n);
      }
    }

    // ---- S = (Q @ K^T) * 0.125 : rows 32 (wave) x cols 64 ----
    f32x4 sc[2][4];
    #pragma unroll
    for (int i = 0; i < 2; ++i)
      #pragma unroll
      for (int j = 0; j < 4; ++j) sc[i][j] = (f32x4){0.f, 0.f, 0.f, 0.f};
    #pragma unroll
    for (int kk = 0; kk < 2; ++kk) {
      bf16x8 bk_f[4];
      #pragma unroll
      for (int j = 0; j < 4; ++j)
        bk_f[j] = *(const bf16x8*)&Ks[(j * 16 + r16) * LDP + kk * 32 + quad * 8];
      #pragma unroll
      for (int i = 0; i < 2; ++i)
        #pragma unroll
        for (int j = 0; j < 4; ++j)
          sc[i][j] = __builtin_amdgcn_mfma_f32_16x16x32_bf16(af_q[i][kk], bk_f[j], sc[i][j], 0, 0, 0);
    }

    // ---- online softmax ----
    float alpha[2][4];
    #pragma unroll
    for (int i = 0; i < 2; ++i) {
      #pragma unroll
      for (int r = 0; r < 4; ++r) {
        float mx = -1e30f;
        #pragma unroll
        for (int j = 0; j < 4; ++j) {
          sc[i][j][r] *= 0.125f;
          mx = fmaxf(mx, sc[i][j][r]);
        }
        #pragma unroll
        for (int msk = 1; msk < 16; msk <<= 1)
          mx = fmaxf(mx, __shfl_xor(mx, msk));
        float m_new = fmaxf(m_s[i][r], mx);
        alpha[i][r] = __expf(m_s[i][r] - m_new);
        m_s[i][r] = m_new;
        float rs = 0.f;
        #pragma unroll
        for (int j = 0; j < 4; ++j) {
          float pv = __expf(sc[i][j][r] - m_new);
          sc[i][j][r] = pv;
          rs += pv;
        }
        #pragma unroll
        for (int msk = 1; msk < 16; msk <<= 1)
          rs += __shfl_xor(rs, msk);
        l_s[i][r] = l_s[i][r] * alpha[i][r] + rs;
        #pragma unroll
        for (int jd = 0; jd < 4; ++jd) O[i][jd][r] *= alpha[i][r];
      }
    }

    // ---- write P (bf16) to LDS in A-readable row-major layout ----
    #pragma unroll
    for (int i = 0; i < 2; ++i) {
      int prow = wq0 + i * 16 + quad * 4;
      #pragma unroll
      for (int j = 0; j < 4; ++j)
        #pragma unroll
        for (int r = 0; r < 4; ++r)
          Ps[(prow + r) * LDP + j * 16 + r16] = __float2bfloat16(sc[i][j][r]);
    }
    __syncthreads();

    // ---- O += P @ V : P[32][64] x V[64 keys][64 d] via VT[d][key] ----
    #pragma unroll
    for (int kk = 0; kk < 2; ++kk) {
      bf16x8 af_p[2], bv_f[4];
      #pragma unroll
      for (int i = 0; i < 2; ++i)
        af_p[i] = *(const bf16x8*)&Ps[(wq0 + i * 16 + r16) * LDP + kk * 32 + quad * 8];
      #pragma unroll
      for (int jd = 0; jd < 4; ++jd)
        bv_f[jd] = *(const bf16x8*)&VTs[(jd * 16 + r16) * LDP + kk * 32 + quad * 8];
      #pragma unroll
      for (int i = 0; i < 2; ++i)
        #pragma unroll
        for (int jd = 0; jd < 4; ++jd)
          O[i][jd] = __builtin_amdgcn_mfma_f32_16x16x32_bf16(af_p[i], bv_f[jd], O[i][jd], 0, 0, 0);
    }
  }

  // ---- epilogue: ctx[s][h*64+d] = O / l ----
  #pragma unroll
  for (int i = 0; i < 2; ++i) {
    #pragma unroll
    for (int r = 0; r < 4; ++r) {
      long row = s0 + wq0 + i * 16 + quad * 4 + r;
      float inv = 1.f / l_s[i][r];
      #pragma unroll
      for (int jd = 0; jd < 4; ++jd)
        ctx[row * 1024 + h * 64 + jd * 16 + r16] = __float2bfloat16(O[i][jd][r] * inv);
    }
  }
}

// fp32 weight [R][C] -> bf16 transposed [C][R]
__global__ __launch_bounds__(256) void transpose_cast(
    const float* __restrict__ in, bf16* __restrict__ out, int R, int C)
{
  __shared__ bf16 tile[32][33];
  const int tx = threadIdx.x, ty = threadIdx.y;
  const int r0 = blockIdx.y * 32, c0 = blockIdx.x * 32;
  #pragma unroll
  for (int d = 0; d < 32; d += 8)
    tile[ty + d][tx] = __float2bfloat16(in[(long)(r0 + ty + d) * C + c0 + tx]);
  __syncthreads();
  #pragma unroll
  for (int d = 0; d < 32; d += 8)
    out[(long)(c0 + ty + d) * R + r0 + tx] = tile[tx][ty + d];
}

// bf16 [R][C] (row stride ldin) -> bf16 transposed [C][R]
__global__ __launch_bounds__(256) void transpose_bf16(
    const bf16* __restrict__ in, bf16* __restrict__ out, int R, int C, int ldin)
{
  __shared__ bf16 tile[32][33];
  const int tx = threadIdx.x, ty = threadIdx.y;
  const int r0 = blockIdx.y * 32, c0 = blockIdx.x * 32;
  #pragma unroll
  for (int d = 0; d < 32; d += 8)
    tile[ty + d][tx] = in[(long)(r0 + ty + d) * ldin + c0 + tx];
  __syncthreads();
  #pragma unroll
  for (int d = 0; d < 32; d += 8)
    out[(long)(c0 + ty + d) * R + r0 + tx] = tile[tx][ty + d];
}

__device__ __forceinline__ float blk_sum(float v, float* sh) {
  #pragma unroll
  for (int o = 32; o > 0; o >>= 1) v += __shfl_down(v, o);
  __syncthreads();
  if ((threadIdx.x & 63) == 0) sh[threadIdx.x >> 6] = v;
  __syncthreads();
  return sh[0] + sh[1] + sh[2] + sh[3];
}

// X = LN(X + d0 + d1 + bias)*g + b, writes bf16 copy to xb. Row = 1024 cols.
__global__ __launch_bounds__(256) void ln_residual2(
    float* __restrict__ X, const float* __restrict__ d0, const float* __restrict__ d1,
    const float* __restrict__ bias,
    const float* __restrict__ g, const float* __restrict__ b,
    bf16* __restrict__ xb)
{
  __shared__ float sh[4];
  const int t = threadIdx.x;
  const long base = (long)blockIdx.x * 1024;
  float v[4]; float s = 0.f;
  #pragma unroll
  for (int i = 0; i < 4; ++i) {
    int c = t + i * 256;
    float val = X[base + c] + d0[base + c] + d1[base + c] + bias[c];
    v[i] = val; s += val;
  }
  s = blk_sum(s, sh);
  const float mu = s * (1.f / 1024.f);
  float s2 = 0.f;
  #pragma unroll
  for (int i = 0; i < 4; ++i) { float d = v[i] - mu; s2 += d * d; }
  s2 = blk_sum(s2, sh);
  const float rs = rsqrtf(s2 * (1.f / 1024.f) + 1e-5f);
  #pragma unroll
  for (int i = 0; i < 4; ++i) {
    int c = t + i * 256;
    float o = (v[i] - mu) * rs * g[c] + b[c];
    X[base + c] = o;
    xb[base + c] = __float2bfloat16(o);
  }
}

__global__ __launch_bounds__(256) void init_x(
    const float* __restrict__ xin, float* __restrict__ X, bf16* __restrict__ xb, int n)
{
  for (int i = blockIdx.x * 256 + threadIdx.x; i < n; i += gridDim.x * 256) {
    float v = xin[i];
    X[i] = v;
    xb[i] = __float2bfloat16(v);
  }
}

__global__ __launch_bounds__(256) void copy_out(
    const float* __restrict__ X, float* __restrict__ out, int n)
{
  for (int i = blockIdx.x * 256 + threadIdx.x; i < n; i += gridDim.x * 256)
    out[i] = X[i];
}

// bias3[l][j][c] = {bq,bk,bv}[l][c]
__global__ __launch_bounds__(256) void concat_bias(
    const float* __restrict__ bq, const float* __restrict__ bk,
    const float* __restrict__ bv, float* __restrict__ out, int n)
{
  for (int i = blockIdx.x * 256 + threadIdx.x; i < n; i += gridDim.x * 256) {
    int l = i / 3072, r = i % 3072;
    int j = r / 1024, c = r % 1024;
    const float* src = (j == 0) ? bq : (j == 1) ? bk : bv;
    out[i] = src[l * 1024 + c];
  }
}

extern "C" void kernel_launch(void* const* d_in, const int* in_sizes, int n_in,
                              void* d_out, int out_size, void* d_ws, size_t ws_size,
                              hipStream_t stream) {
  constexpr int S = 2048, D = 1024, F = 4096, L = 4;
  const float* xin = (const float*)d_in[0];
  const float* wq = (const float*)d_in[1];
  const float* bq = (const float*)d_in[2];
  const float* wk = (const float*)d_in[3];
  const float* bk = (const float*)d_in[4];
  const float* wv = (const float*)d_in[5];
  const float* bvp = (const float*)d_in[6];
  const float* wo = (const float*)d_in[7];
  const float* bo = (const float*)d_in[8];
  const float* w1 = (const float*)d_in[9];
  const float* b1 = (const float*)d_in[10];
  const float* w2 = (const float*)d_in[11];
  const float* b2 = (const float*)d_in[12];
  const float* ln1g = (const float*)d_in[13];
  const float* ln1b = (const float*)d_in[14];
  const float* ln2g = (const float*)d_in[15];
  const float* ln2b = (const float*)d_in[16];

  // workspace ~56 MB (<= 64 MB proven). hb overlays qkv+ctx (16 MB).
  char* p = (char*)d_ws;
  float* X    = (float*)p; p += (long)S * D * 4;        // 8 MB
  float* tmpf = (float*)p; p += 2L * S * D * 4;         // 16 MB (2 split-K slabs)
  bf16* xb    = (bf16*)p;  p += (long)S * D * 2;        // 4 MB
  bf16* qkv   = (bf16*)p;                               // 12 MB
  bf16* hb    = (bf16*)p;  p += (long)S * 3 * D * 2;    // hb overlays qkv..ctx
  bf16* ctx   = (bf16*)p;  p += (long)S * D * 2;        // 4 MB
  bf16* vT    = (bf16*)p;  p += (long)S * D * 2;        // 4 MB  [H*64][S]
  bf16* wT    = (bf16*)p;  p += (long)F * D * 2;        // 8 MB
  float* bias3= (float*)p; p += (long)L * 3 * D * 4;    // 48 KB

  init_x<<<2048, 256, 0, stream>>>(xin, X, xb, S * D);
  concat_bias<<<48, 256, 0, stream>>>(bq, bk, bvp, bias3, L * 3 * D);

  for (int l = 0; l < L; ++l) {
    // fused QKV
    transpose_cast<<<dim3(D / 32, D / 32), dim3(32, 8), 0, stream>>>(wq + (long)l * D * D, wT, D, D);
    transpose_cast<<<dim3(D / 32, D / 32), dim3(32, 8), 0, stream>>>(wk + (long)l * D * D, wT + (long)D * D, D, D);
    transpose_cast<<<dim3(D / 32, D / 32), dim3(32, 8), 0, stream>>>(wv + (long)l * D * D, wT + 2L * D * D, D, D);
    gemm_bt<128, 128, EPI_BIAS_BF16, bf16><<<dim3(3 * D / 128, S / 128, 1), 256, 0, stream>>>(
        xb, 0L, D, wT, 0L, D, qkv, 0L, 3 * D, bias3 + l * 3 * D, D, 1.f);

    // vT[h*64+d][s]
    transpose_bf16<<<dim3(D / 32, S / 32), dim3(32, 8), 0, stream>>>(qkv + 2 * D, vT, S, D, 3 * D);

    // fused attention
    flash_attn<<<dim3(S / 128, 16), 256, 0, stream>>>(qkv, vT, ctx);

    // attn-out, split-K 2 -> fp32 slabs
    transpose_cast<<<dim3(D / 32, D / 32), dim3(32, 8), 0, stream>>>(wo + (long)l * D * D, wT, D, D);
    gemm_bt<128, 64, EPI_NONE, float><<<dim3(D / 64, S / 128, 2), 256, 0, stream>>>(
        ctx, (long)(D / 2), D, wT, (long)(D / 2), D, tmpf, (long)S * D, D, nullptr, D / 2, 1.f);
    ln_residual2<<<S, 256, 0, stream>>>(X, tmpf, tmpf + (long)S * D, bo + l * D,
                                        ln1g + l * D, ln1b + l * D, xb);

    // FFN
    transpose_cast<<<dim3(F / 32, D / 32), dim3(32, 8), 0, stream>>>(w1 + (long)l * D * F, wT, D, F);
    gemm_bt<128, 128, EPI_BIAS_GELU_BF16, bf16><<<dim3(F / 128, S / 128, 1), 256, 0, stream>>>(
        xb, 0L, D, wT, 0L, D, hb, 0L, F, b1 + l * F, D, 1.f);
    transpose_cast<<<dim3(D / 32, F / 32), dim3(32, 8), 0, stream>>>(w2 + (long)l * F * D, wT, F, D);
    gemm_bt<128, 64, EPI_NONE, float><<<dim3(D / 64, S / 128, 2), 256, 0, stream>>>(
        hb, (long)(F / 2), F, wT, (long)(F / 2), F, tmpf, (long)S * D, D, nullptr, F / 2, 1.f);
    ln_residual2<<<S, 256, 0, stream>>>(X, tmpf, tmpf + (long)S * D, b2 + l * D,
                                        ln2g + l * D, ln2b + l * D, xb);
  }
  copy_out<<<2048, 256, 0, stream>>>(X, (float*)d_out, S * D);
}

// Round 6
// 1240.664 us; speedup vs baseline: 3.7048x; 1.5082x over previous
//
#include <hip/hip_runtime.h>
#include <hip/hip_bf16.h>
#include <math.h>

typedef __hip_bfloat16 bf16;
typedef __attribute__((ext_vector_type(8))) short bf16x8;
typedef __attribute__((ext_vector_type(4))) float f32x4;

#define EPI_NONE 0
#define EPI_BIAS_BF16 1
#define EPI_BIAS_GELU_BF16 2

__device__ __forceinline__ void gload16(const void* g, void* l) {
  __builtin_amdgcn_global_load_lds((const __attribute__((address_space(1))) void*)g,
                                   (__attribute__((address_space(3))) void*)l, 16, 0, 0);
}

__device__ __forceinline__ float gelu_tanh(float x) {
  const float c = 0.7978845608028654f;
  float t = tanhf(c * (x + 0.044715f * x * x * x));
  return 0.5f * x * (1.0f + t);
}

// C = A @ Bt^T (+bias, epilogue). A:[M][K] bf16 lda, Bt:[N][K] bf16 ldb.
// z: generic slab offsets (split-K). 256 thr = 4 waves, wave tile (BM/2)x(BN/2).
// Staging: m97-style global_load_lds width-16 (async DMA, no VGPR round trip).
template<int BM, int BN, int EPI, typename CT>
__global__ __launch_bounds__(256) void gemm_bt(
    const bf16* __restrict__ A, long sAz, int lda,
    const bf16* __restrict__ Bt, long sBz, int ldb,
    CT* __restrict__ C, long sCz, int ldc,
    const float* __restrict__ bias,
    int K, float scale)
{
  constexpr int BK = 32;
  constexpr int WM = BM / 2, WN = BN / 2;
  constexpr int MI = WM / 16, NJ = WN / 16;
  constexpr int NA = (BM * BK * 2) / 4096;
  constexpr int NB = (BN * BK * 2) / 4096;
  __shared__ __align__(16) bf16 As[BM * BK];
  __shared__ __align__(16) bf16 Bs[BN * BK];
  const int t = threadIdx.x;
  const int lane = t & 63, w = t >> 6;
  const int wm = (w >> 1) * WM, wn = (w & 1) * WN;
  const int quad = lane >> 4, r16 = lane & 15;
  const long z = blockIdx.z;
  const bf16* Ab = A + z * sAz + (long)blockIdx.y * BM * lda;
  const bf16* Bb = Bt + z * sBz + (long)blockIdx.x * BN * ldb;

  f32x4 acc[MI][NJ];
  #pragma unroll
  for (int i = 0; i < MI; ++i)
    #pragma unroll
    for (int j = 0; j < NJ; ++j)
      acc[i][j] = (f32x4){0.f, 0.f, 0.f, 0.f};

  for (int k0 = 0; k0 < K; k0 += BK) {
    __syncthreads();
    #pragma unroll
    for (int s = 0; s < NA; ++s) {
      int Lb = s * 4096 + t * 16;
      int row = Lb >> 6, colb = Lb & 63;          // 64 B per LDS row (32 bf16)
      gload16((const char*)Ab + (long)row * (lda * 2) + k0 * 2 + colb, (char*)As + Lb);
    }
    #pragma unroll
    for (int s = 0; s < NB; ++s) {
      int Lb = s * 4096 + t * 16;
      int row = Lb >> 6, colb = Lb & 63;
      gload16((const char*)Bb + (long)row * (ldb * 2) + k0 * 2 + colb, (char*)Bs + Lb);
    }
    __syncthreads();   // vmcnt(0) drain before barrier (compiler-inserted)

    bf16x8 af[MI], bfv[NJ];
    #pragma unroll
    for (int i = 0; i < MI; ++i)
      af[i] = *(const bf16x8*)&As[(wm + i * 16 + r16) * BK + quad * 8];
    #pragma unroll
    for (int j = 0; j < NJ; ++j)
      bfv[j] = *(const bf16x8*)&Bs[(wn + j * 16 + r16) * BK + quad * 8];
    #pragma unroll
    for (int i = 0; i < MI; ++i)
      #pragma unroll
      for (int j = 0; j < NJ; ++j)
        acc[i][j] = __builtin_amdgcn_mfma_f32_16x16x32_bf16(af[i], bfv[j], acc[i][j], 0, 0, 0);
  }

  CT* Cb = C + z * sCz;
  #pragma unroll
  for (int i = 0; i < MI; ++i) {
    #pragma unroll
    for (int j = 0; j < NJ; ++j) {
      int col = blockIdx.x * BN + wn + j * 16 + r16;
      float bvv = 0.f;
      if constexpr (EPI == EPI_BIAS_BF16 || EPI == EPI_BIAS_GELU_BF16)
        bvv = bias[col];
      #pragma unroll
      for (int r = 0; r < 4; ++r) {
        long row = (long)blockIdx.y * BM + wm + i * 16 + quad * 4 + r;
        float val = acc[i][j][r] * scale + bvv;
        if constexpr (EPI == EPI_BIAS_GELU_BF16) val = gelu_tanh(val);
        if constexpr (sizeof(CT) == 2)
          Cb[row * (long)ldc + col] = __float2bfloat16(val);
        else
          Cb[row * (long)ldc + col] = val;
      }
    }
  }
}

// Fused flash attention v2: per block = (64-row Q tile, one head). Grid (32,16)=512.
// LDS ~35 KB -> 4 blocks/CU cap; wave tile 16 Q rows.
__global__ __launch_bounds__(256) void flash_attn(
    const bf16* __restrict__ qkv, const bf16* __restrict__ vT,
    bf16* __restrict__ ctx)
{
  constexpr int SEQ = 2048, LDP = 72;
  __shared__ __align__(16) bf16 Qs[64 * 64];
  __shared__ __align__(16) bf16 Ks[64 * LDP];
  __shared__ __align__(16) bf16 VTs[64 * LDP];
  __shared__ __align__(16) bf16 Ps[64 * LDP];

  const int t = threadIdx.x;
  const int lane = t & 63, w = t >> 6;
  const int quad = lane >> 4, r16 = lane & 15;
  const int wq0 = w * 16;                 // wave's 16 Q rows within tile
  const int s0 = blockIdx.x * 64;
  const int h = blockIdx.y;

  // ---- stage Q tile [64][64] (register route, unpadded) ----
  #pragma unroll
  for (int s = 0; s < 2; ++s) {
    int Lb = s * 4096 + t * 16;
    int row = Lb >> 7, colb = Lb & 127;
    int4 v = *(const int4*)(qkv + (long)(s0 + row) * 3072 + h * 64 + (colb >> 1));
    *(int4*)((char*)Qs + Lb) = v;
  }

  // K/V staging pointers
  const bf16* kp[2]; const bf16* vp[2];
  int krow[2], kcolb[2];
  #pragma unroll
  for (int s = 0; s < 2; ++s) {
    int Lb = s * 4096 + t * 16;
    krow[s] = Lb >> 7; kcolb[s] = Lb & 127;
    kp[s] = qkv + 1024 + (long)h * 64 + (long)krow[s] * 3072 + (kcolb[s] >> 1);
    vp[s] = vT + (long)(h * 64 + krow[s]) * SEQ + (kcolb[s] >> 1);
  }

  int4 rk[2], rv[2];
  #pragma unroll
  for (int s = 0; s < 2; ++s) {
    rk[s] = *(const int4*)(kp[s]);
    rv[s] = *(const int4*)(vp[s]);
  }

  __syncthreads();
  bf16x8 af_q[2];
  #pragma unroll
  for (int kk = 0; kk < 2; ++kk)
    af_q[kk] = *(const bf16x8*)&Qs[(wq0 + r16) * 64 + kk * 32 + quad * 8];

  f32x4 O[4];
  float m_s[4], l_s[4];
  #pragma unroll
  for (int jd = 0; jd < 4; ++jd) O[jd] = (f32x4){0.f, 0.f, 0.f, 0.f};
  #pragma unroll
  for (int r = 0; r < 4; ++r) { m_s[r] = -1e30f; l_s[r] = 0.f; }

  for (int kt = 0; kt < SEQ / 64; ++kt) {
    __syncthreads();
    #pragma unroll
    for (int s = 0; s < 2; ++s) {
      *(int4*)((char*)Ks + (krow[s] * LDP * 2) + kcolb[s]) = rk[s];
      *(int4*)((char*)VTs + (krow[s] * LDP * 2) + kcolb[s]) = rv[s];
    }
    __syncthreads();

    if (kt + 1 < SEQ / 64) {
      long k0n = (long)(kt + 1) * 64;
      #pragma unroll
      for (int s = 0; s < 2; ++s) {
        rk[s] = *(const int4*)(kp[s] + k0n * 3072);
        rv[s] = *(const int4*)(vp[s] + k0n);
      }
    }

    // ---- S = (Q @ K^T) * 0.125 : 16 rows x 64 cols ----
    f32x4 sc[4];
    #pragma unroll
    for (int j = 0; j < 4; ++j) sc[j] = (f32x4){0.f, 0.f, 0.f, 0.f};
    #pragma unroll
    for (int kk = 0; kk < 2; ++kk) {
      bf16x8 bk_f[4];
      #pragma unroll
      for (int j = 0; j < 4; ++j)
        bk_f[j] = *(const bf16x8*)&Ks[(j * 16 + r16) * LDP + kk * 32 + quad * 8];
      #pragma unroll
      for (int j = 0; j < 4; ++j)
        sc[j] = __builtin_amdgcn_mfma_f32_16x16x32_bf16(af_q[kk], bk_f[j], sc[j], 0, 0, 0);
    }

    // ---- online softmax (per lane: rows quad*4+r, cols r16 across 4 j-tiles) ----
    #pragma unroll
    for (int r = 0; r < 4; ++r) {
      float mx = -1e30f;
      #pragma unroll
      for (int j = 0; j < 4; ++j) {
        sc[j][r] *= 0.125f;
        mx = fmaxf(mx, sc[j][r]);
      }
      #pragma unroll
      for (int msk = 1; msk < 16; msk <<= 1)
        mx = fmaxf(mx, __shfl_xor(mx, msk));
      float m_new = fmaxf(m_s[r], mx);
      float alpha = __expf(m_s[r] - m_new);
      m_s[r] = m_new;
      float rs = 0.f;
      #pragma unroll
      for (int j = 0; j < 4; ++j) {
        float pv = __expf(sc[j][r] - m_new);
        sc[j][r] = pv;
        rs += pv;
      }
      #pragma unroll
      for (int msk = 1; msk < 16; msk <<= 1)
        rs += __shfl_xor(rs, msk);
      l_s[r] = l_s[r] * alpha + rs;
      #pragma unroll
      for (int jd = 0; jd < 4; ++jd) O[jd][r] *= alpha;
    }

    // ---- P (bf16) to LDS in A-readable row-major layout ----
    {
      int prow = wq0 + quad * 4;
      #pragma unroll
      for (int j = 0; j < 4; ++j)
        #pragma unroll
        for (int r = 0; r < 4; ++r)
          Ps[(prow + r) * LDP + j * 16 + r16] = __float2bfloat16(sc[j][r]);
    }
    __syncthreads();

    // ---- O += P @ V via VT[d][key] ----
    #pragma unroll
    for (int kk = 0; kk < 2; ++kk) {
      bf16x8 af_p, bv_f[4];
      af_p = *(const bf16x8*)&Ps[(wq0 + r16) * LDP + kk * 32 + quad * 8];
      #pragma unroll
      for (int jd = 0; jd < 4; ++jd)
        bv_f[jd] = *(const bf16x8*)&VTs[(jd * 16 + r16) * LDP + kk * 32 + quad * 8];
      #pragma unroll
      for (int jd = 0; jd < 4; ++jd)
        O[jd] = __builtin_amdgcn_mfma_f32_16x16x32_bf16(af_p, bv_f[jd], O[jd], 0, 0, 0);
    }
  }

  // ---- epilogue ----
  #pragma unroll
  for (int r = 0; r < 4; ++r) {
    long row = s0 + wq0 + quad * 4 + r;
    float inv = 1.f / l_s[r];
    #pragma unroll
    for (int jd = 0; jd < 4; ++jd)
      ctx[row * 1024 + h * 64 + jd * 16 + r16] = __float2bfloat16(O[jd][r] * inv);
  }
}

// fp32 weight [R][C] -> bf16 transposed [C][R]
__global__ __launch_bounds__(256) void transpose_cast(
    const float* __restrict__ in, bf16* __restrict__ out, int R, int C)
{
  __shared__ bf16 tile[32][33];
  const int tx = threadIdx.x, ty = threadIdx.y;
  const int r0 = blockIdx.y * 32, c0 = blockIdx.x * 32;
  #pragma unroll
  for (int d = 0; d < 32; d += 8)
    tile[ty + d][tx] = __float2bfloat16(in[(long)(r0 + ty + d) * C + c0 + tx]);
  __syncthreads();
  #pragma unroll
  for (int d = 0; d < 32; d += 8)
    out[(long)(c0 + ty + d) * R + r0 + tx] = tile[tx][ty + d];
}

// bf16 [R][C] (row stride ldin) -> bf16 transposed [C][R]
__global__ __launch_bounds__(256) void transpose_bf16(
    const bf16* __restrict__ in, bf16* __restrict__ out, int R, int C, int ldin)
{
  __shared__ bf16 tile[32][33];
  const int tx = threadIdx.x, ty = threadIdx.y;
  const int r0 = blockIdx.y * 32, c0 = blockIdx.x * 32;
  #pragma unroll
  for (int d = 0; d < 32; d += 8)
    tile[ty + d][tx] = in[(long)(r0 + ty + d) * ldin + c0 + tx];
  __syncthreads();
  #pragma unroll
  for (int d = 0; d < 32; d += 8)
    out[(long)(c0 + ty + d) * R + r0 + tx] = tile[tx][ty + d];
}

__device__ __forceinline__ float blk_sum(float v, float* sh) {
  #pragma unroll
  for (int o = 32; o > 0; o >>= 1) v += __shfl_down(v, o);
  __syncthreads();
  if ((threadIdx.x & 63) == 0) sh[threadIdx.x >> 6] = v;
  __syncthreads();
  return sh[0] + sh[1] + sh[2] + sh[3];
}

// X = LN(X + d0 + d1 + bias)*g + b, writes bf16 copy to xb.
__global__ __launch_bounds__(256) void ln_residual2(
    float* __restrict__ X, const float* __restrict__ d0, const float* __restrict__ d1,
    const float* __restrict__ bias,
    const float* __restrict__ g, const float* __restrict__ b,
    bf16* __restrict__ xb)
{
  __shared__ float sh[4];
  const int t = threadIdx.x;
  const long base = (long)blockIdx.x * 1024;
  float v[4]; float s = 0.f;
  #pragma unroll
  for (int i = 0; i < 4; ++i) {
    int c = t + i * 256;
    float val = X[base + c] + d0[base + c] + d1[base + c] + bias[c];
    v[i] = val; s += val;
  }
  s = blk_sum(s, sh);
  const float mu = s * (1.f / 1024.f);
  float s2 = 0.f;
  #pragma unroll
  for (int i = 0; i < 4; ++i) { float d = v[i] - mu; s2 += d * d; }
  s2 = blk_sum(s2, sh);
  const float rs = rsqrtf(s2 * (1.f / 1024.f) + 1e-5f);
  #pragma unroll
  for (int i = 0; i < 4; ++i) {
    int c = t + i * 256;
    float o = (v[i] - mu) * rs * g[c] + b[c];
    X[base + c] = o;
    xb[base + c] = __float2bfloat16(o);
  }
}

__global__ __launch_bounds__(256) void init_x(
    const float* __restrict__ xin, float* __restrict__ X, bf16* __restrict__ xb, int n)
{
  for (int i = blockIdx.x * 256 + threadIdx.x; i < n; i += gridDim.x * 256) {
    float v = xin[i];
    X[i] = v;
    xb[i] = __float2bfloat16(v);
  }
}

__global__ __launch_bounds__(256) void copy_out(
    const float* __restrict__ X, float* __restrict__ out, int n)
{
  for (int i = blockIdx.x * 256 + threadIdx.x; i < n; i += gridDim.x * 256)
    out[i] = X[i];
}

// bias3[l][j][c] = {bq,bk,bv}[l][c]
__global__ __launch_bounds__(256) void concat_bias(
    const float* __restrict__ bq, const float* __restrict__ bk,
    const float* __restrict__ bv, float* __restrict__ out, int n)
{
  for (int i = blockIdx.x * 256 + threadIdx.x; i < n; i += gridDim.x * 256) {
    int l = i / 3072, r = i % 3072;
    int j = r / 1024, c = r % 1024;
    const float* src = (j == 0) ? bq : (j == 1) ? bk : bv;
    out[i] = src[l * 1024 + c];
  }
}

extern "C" void kernel_launch(void* const* d_in, const int* in_sizes, int n_in,
                              void* d_out, int out_size, void* d_ws, size_t ws_size,
                              hipStream_t stream) {
  constexpr int S = 2048, D = 1024, F = 4096, L = 4;
  const float* xin = (const float*)d_in[0];
  const float* wq = (const float*)d_in[1];
  const float* bq = (const float*)d_in[2];
  const float* wk = (const float*)d_in[3];
  const float* bk = (const float*)d_in[4];
  const float* wv = (const float*)d_in[5];
  const float* bvp = (const float*)d_in[6];
  const float* wo = (const float*)d_in[7];
  const float* bo = (const float*)d_in[8];
  const float* w1 = (const float*)d_in[9];
  const float* b1 = (const float*)d_in[10];
  const float* w2 = (const float*)d_in[11];
  const float* b2 = (const float*)d_in[12];
  const float* ln1g = (const float*)d_in[13];
  const float* ln1b = (const float*)d_in[14];
  const float* ln2g = (const float*)d_in[15];
  const float* ln2b = (const float*)d_in[16];

  // workspace ~56 MB (<= 64 MB proven). hb overlays qkv+ctx.
  char* p = (char*)d_ws;
  float* X    = (float*)p; p += (long)S * D * 4;        // 8 MB
  float* tmpf = (float*)p; p += 2L * S * D * 4;         // 16 MB (2 split-K slabs)
  bf16* xb    = (bf16*)p;  p += (long)S * D * 2;        // 4 MB
  bf16* qkv   = (bf16*)p;                               // 12 MB
  bf16* hb    = (bf16*)p;  p += (long)S * 3 * D * 2;    // hb overlays qkv..ctx
  bf16* ctx   = (bf16*)p;  p += (long)S * D * 2;        // 4 MB
  bf16* vT    = (bf16*)p;  p += (long)S * D * 2;        // 4 MB  [H*64][S]
  bf16* wT    = (bf16*)p;  p += (long)F * D * 2;        // 8 MB
  float* bias3= (float*)p; p += (long)L * 3 * D * 4;    // 48 KB

  init_x<<<2048, 256, 0, stream>>>(xin, X, xb, S * D);
  concat_bias<<<48, 256, 0, stream>>>(bq, bk, bvp, bias3, L * 3 * D);

  for (int l = 0; l < L; ++l) {
    // fused QKV
    transpose_cast<<<dim3(D / 32, D / 32), dim3(32, 8), 0, stream>>>(wq + (long)l * D * D, wT, D, D);
    transpose_cast<<<dim3(D / 32, D / 32), dim3(32, 8), 0, stream>>>(wk + (long)l * D * D, wT + (long)D * D, D, D);
    transpose_cast<<<dim3(D / 32, D / 32), dim3(32, 8), 0, stream>>>(wv + (long)l * D * D, wT + 2L * D * D, D, D);
    gemm_bt<128, 128, EPI_BIAS_BF16, bf16><<<dim3(3 * D / 128, S / 128, 1), 256, 0, stream>>>(
        xb, 0L, D, wT, 0L, D, qkv, 0L, 3 * D, bias3 + l * 3 * D, D, 1.f);

    // vT[h*64+d][s]
    transpose_bf16<<<dim3(D / 32, S / 32), dim3(32, 8), 0, stream>>>(qkv + 2 * D, vT, S, D, 3 * D);

    // fused attention
    flash_attn<<<dim3(S / 64, 16), 256, 0, stream>>>(qkv, vT, ctx);

    // attn-out, split-K 2 -> fp32 slabs
    transpose_cast<<<dim3(D / 32, D / 32), dim3(32, 8), 0, stream>>>(wo + (long)l * D * D, wT, D, D);
    gemm_bt<128, 64, EPI_NONE, float><<<dim3(D / 64, S / 128, 2), 256, 0, stream>>>(
        ctx, (long)(D / 2), D, wT, (long)(D / 2), D, tmpf, (long)S * D, D, nullptr, D / 2, 1.f);
    ln_residual2<<<S, 256, 0, stream>>>(X, tmpf, tmpf + (long)S * D, bo + l * D,
                                        ln1g + l * D, ln1b + l * D, xb);

    // FFN
    transpose_cast<<<dim3(F / 32, D / 32), dim3(32, 8), 0, stream>>>(w1 + (long)l * D * F, wT, D, F);
    gemm_bt<128, 128, EPI_BIAS_GELU_BF16, bf16><<<dim3(F / 128, S / 128, 1), 256, 0, stream>>>(
        xb, 0L, D, wT, 0L, D, hb, 0L, F, b1 + l * F, D, 1.f);
    transpose_cast<<<dim3(D / 32, F / 32), dim3(32, 8), 0, stream>>>(w2 + (long)l * F * D, wT, F, D);
    gemm_bt<128, 64, EPI_NONE, float><<<dim3(D / 64, S / 128, 2), 256, 0, stream>>>(
        hb, (long)(F / 2), F, wT, (long)(F / 2), F, tmpf, (long)S * D, D, nullptr, F / 2, 1.f);
    ln_residual2<<<S, 256, 0, stream>>>(X, tmpf, tmpf + (long)S * D, b2 + l * D,
                                        ln2g + l * D, ln2b + l * D, xb);
  }
  copy_out<<<2048, 256, 0, stream>>>(X, (float*)d_out, S * D);
}

// Round 7
// 1203.814 us; speedup vs baseline: 3.8182x; 1.0306x over previous
//
#include <hip/hip_runtime.h>
#include <hip/hip_bf16.h>
#include <math.h>

typedef __hip_bfloat16 bf16;
typedef __attribute__((ext_vector_type(8))) short bf16x8;
typedef __attribute__((ext_vector_type(4))) float f32x4;

#define EPI_NONE 0
#define EPI_BIAS_BF16 1
#define EPI_BIAS_GELU_BF16 2

#define CLOG 0.18033688f   // 0.125 * log2(e) — attention scale folded into exp2

__device__ __forceinline__ void gload16(const void* g, void* l) {
  __builtin_amdgcn_global_load_lds((const __attribute__((address_space(1))) void*)g,
                                   (__attribute__((address_space(3))) void*)l, 16, 0, 0);
}

__device__ __forceinline__ float gelu_tanh(float x) {
  const float c = 0.7978845608028654f;
  float t = tanhf(c * (x + 0.044715f * x * x * x));
  return 0.5f * x * (1.0f + t);
}

// C = A @ Bt^T (+bias, epilogue). A:[M][K] bf16 lda, Bt:[N][K] bf16 ldb.
// z: generic slab offsets (split-K). 256 thr = 4 waves, wave tile (BM/2)x(BN/2).
// global_load_lds width-16 staging; BK=64 halves barrier count vs BK=32.
template<int BM, int BN, int BK, int EPI, typename CT>
__global__ __launch_bounds__(256) void gemm_bt(
    const bf16* __restrict__ A, long sAz, int lda,
    const bf16* __restrict__ Bt, long sBz, int ldb,
    CT* __restrict__ C, long sCz, int ldc,
    const float* __restrict__ bias,
    int K, float scale)
{
  constexpr int WM = BM / 2, WN = BN / 2;
  constexpr int MI = WM / 16, NJ = WN / 16;
  constexpr int NA = (BM * BK * 2) / 4096;
  constexpr int NB = (BN * BK * 2) / 4096;
  constexpr int ROWB = BK * 2;          // bytes per LDS row
  __shared__ __align__(16) bf16 As[BM * BK];
  __shared__ __align__(16) bf16 Bs[BN * BK];
  const int t = threadIdx.x;
  const int lane = t & 63, w = t >> 6;
  const int wm = (w >> 1) * WM, wn = (w & 1) * WN;
  const int quad = lane >> 4, r16 = lane & 15;
  const long z = blockIdx.z;
  const bf16* Ab = A + z * sAz + (long)blockIdx.y * BM * lda;
  const bf16* Bb = Bt + z * sBz + (long)blockIdx.x * BN * ldb;

  f32x4 acc[MI][NJ];
  #pragma unroll
  for (int i = 0; i < MI; ++i)
    #pragma unroll
    for (int j = 0; j < NJ; ++j)
      acc[i][j] = (f32x4){0.f, 0.f, 0.f, 0.f};

  for (int k0 = 0; k0 < K; k0 += BK) {
    __syncthreads();
    #pragma unroll
    for (int s = 0; s < NA; ++s) {
      int Lb = s * 4096 + t * 16;
      int row = Lb / ROWB, colb = Lb % ROWB;
      gload16((const char*)Ab + (long)row * (lda * 2) + k0 * 2 + colb, (char*)As + Lb);
    }
    #pragma unroll
    for (int s = 0; s < NB; ++s) {
      int Lb = s * 4096 + t * 16;
      int row = Lb / ROWB, colb = Lb % ROWB;
      gload16((const char*)Bb + (long)row * (ldb * 2) + k0 * 2 + colb, (char*)Bs + Lb);
    }
    __syncthreads();   // vmcnt(0) drain before barrier (compiler-inserted)

    #pragma unroll
    for (int kk = 0; kk < BK / 32; ++kk) {
      bf16x8 af[MI], bfv[NJ];
      #pragma unroll
      for (int i = 0; i < MI; ++i)
        af[i] = *(const bf16x8*)&As[(wm + i * 16 + r16) * BK + kk * 32 + quad * 8];
      #pragma unroll
      for (int j = 0; j < NJ; ++j)
        bfv[j] = *(const bf16x8*)&Bs[(wn + j * 16 + r16) * BK + kk * 32 + quad * 8];
      #pragma unroll
      for (int i = 0; i < MI; ++i)
        #pragma unroll
        for (int j = 0; j < NJ; ++j)
          acc[i][j] = __builtin_amdgcn_mfma_f32_16x16x32_bf16(af[i], bfv[j], acc[i][j], 0, 0, 0);
    }
  }

  CT* Cb = C + z * sCz;
  #pragma unroll
  for (int i = 0; i < MI; ++i) {
    #pragma unroll
    for (int j = 0; j < NJ; ++j) {
      int col = blockIdx.x * BN + wn + j * 16 + r16;
      float bvv = 0.f;
      if constexpr (EPI == EPI_BIAS_BF16 || EPI == EPI_BIAS_GELU_BF16)
        bvv = bias[col];
      #pragma unroll
      for (int r = 0; r < 4; ++r) {
        long row = (long)blockIdx.y * BM + wm + i * 16 + quad * 4 + r;
        float val = acc[i][j][r] * scale + bvv;
        if constexpr (EPI == EPI_BIAS_GELU_BF16) val = gelu_tanh(val);
        if constexpr (sizeof(CT) == 2)
          Cb[row * (long)ldc + col] = __float2bfloat16(val);
        else
          Cb[row * (long)ldc + col] = val;
      }
    }
  }
}

// Key-split flash attention: block = (64-row Q tile, head, key-split of 1024).
// Grid (32,16,2)=1024 blocks -> 4 blocks/CU. Writes unnormalized fp32 O into
// Osp slab [split][S][1024] and (m,l) float2 into ml[split][head][S].
__global__ __launch_bounds__(256) void flash_attn(
    const bf16* __restrict__ qkv, const bf16* __restrict__ vT,
    float* __restrict__ Osp, float2* __restrict__ ml)
{
  constexpr int SEQ = 2048, LDP = 72;
  __shared__ __align__(16) bf16 Qs[64 * 64];
  __shared__ __align__(16) bf16 Ks[64 * LDP];
  __shared__ __align__(16) bf16 VTs[64 * LDP];
  __shared__ __align__(16) bf16 Ps[64 * LDP];

  const int t = threadIdx.x;
  const int lane = t & 63, w = t >> 6;
  const int quad = lane >> 4, r16 = lane & 15;
  const int wq0 = w * 16;
  const int s0 = blockIdx.x * 64;
  const int h = blockIdx.y;
  const int split = blockIdx.z;
  const int kt0 = split * 16, ktN = kt0 + 16;   // 16 K-tiles of 64 keys each

  // stage Q tile [64][64]
  #pragma unroll
  for (int s = 0; s < 2; ++s) {
    int Lb = s * 4096 + t * 16;
    int row = Lb >> 7, colb = Lb & 127;
    int4 v = *(const int4*)(qkv + (long)(s0 + row) * 3072 + h * 64 + (colb >> 1));
    *(int4*)((char*)Qs + Lb) = v;
  }

  const bf16* kp[2]; const bf16* vp[2];
  int krow[2], kcolb[2];
  #pragma unroll
  for (int s = 0; s < 2; ++s) {
    int Lb = s * 4096 + t * 16;
    krow[s] = Lb >> 7; kcolb[s] = Lb & 127;
    kp[s] = qkv + 1024 + (long)h * 64 + (long)krow[s] * 3072 + (kcolb[s] >> 1);
    vp[s] = vT + (long)(h * 64 + krow[s]) * SEQ + (kcolb[s] >> 1);
  }

  int4 rk[2], rv[2];
  #pragma unroll
  for (int s = 0; s < 2; ++s) {
    rk[s] = *(const int4*)(kp[s] + (long)kt0 * 64 * 3072);
    rv[s] = *(const int4*)(vp[s] + (long)kt0 * 64);
  }

  __syncthreads();
  bf16x8 af_q[2];
  #pragma unroll
  for (int kk = 0; kk < 2; ++kk)
    af_q[kk] = *(const bf16x8*)&Qs[(wq0 + r16) * 64 + kk * 32 + quad * 8];

  f32x4 O[4];
  float m_s[4], l_s[4];   // m in exp2 (C-scaled) domain
  #pragma unroll
  for (int jd = 0; jd < 4; ++jd) O[jd] = (f32x4){0.f, 0.f, 0.f, 0.f};
  #pragma unroll
  for (int r = 0; r < 4; ++r) { m_s[r] = -1e30f; l_s[r] = 0.f; }

  for (int kt = kt0; kt < ktN; ++kt) {
    __syncthreads();
    #pragma unroll
    for (int s = 0; s < 2; ++s) {
      *(int4*)((char*)Ks + (krow[s] * LDP * 2) + kcolb[s]) = rk[s];
      *(int4*)((char*)VTs + (krow[s] * LDP * 2) + kcolb[s]) = rv[s];
    }
    __syncthreads();

    if (kt + 1 < ktN) {
      long k0n = (long)(kt + 1) * 64;
      #pragma unroll
      for (int s = 0; s < 2; ++s) {
        rk[s] = *(const int4*)(kp[s] + k0n * 3072);
        rv[s] = *(const int4*)(vp[s] + k0n);
      }
    }

    // S = Q @ K^T (raw; scale folded into exp2 constant)
    f32x4 sc[4];
    #pragma unroll
    for (int j = 0; j < 4; ++j) sc[j] = (f32x4){0.f, 0.f, 0.f, 0.f};
    #pragma unroll
    for (int kk = 0; kk < 2; ++kk) {
      bf16x8 bk_f[4];
      #pragma unroll
      for (int j = 0; j < 4; ++j)
        bk_f[j] = *(const bf16x8*)&Ks[(j * 16 + r16) * LDP + kk * 32 + quad * 8];
      #pragma unroll
      for (int j = 0; j < 4; ++j)
        sc[j] = __builtin_amdgcn_mfma_f32_16x16x32_bf16(af_q[kk], bk_f[j], sc[j], 0, 0, 0);
    }

    // online softmax in exp2 domain
    #pragma unroll
    for (int r = 0; r < 4; ++r) {
      float mx = fmaxf(fmaxf(sc[0][r], sc[1][r]), fmaxf(sc[2][r], sc[3][r]));
      #pragma unroll
      for (int msk = 1; msk < 16; msk <<= 1)
        mx = fmaxf(mx, __shfl_xor(mx, msk));
      float m_new = fmaxf(m_s[r], mx * CLOG);
      float alpha = exp2f(m_s[r] - m_new);
      m_s[r] = m_new;
      float rs = 0.f;
      #pragma unroll
      for (int j = 0; j < 4; ++j) {
        float pv = exp2f(fmaf(sc[j][r], CLOG, -m_new));
        sc[j][r] = pv;
        rs += pv;
      }
      #pragma unroll
      for (int msk = 1; msk < 16; msk <<= 1)
        rs += __shfl_xor(rs, msk);
      l_s[r] = l_s[r] * alpha + rs;
      #pragma unroll
      for (int jd = 0; jd < 4; ++jd) O[jd][r] *= alpha;
    }

    // P -> LDS (A-layout)
    {
      int prow = wq0 + quad * 4;
      #pragma unroll
      for (int j = 0; j < 4; ++j)
        #pragma unroll
        for (int r = 0; r < 4; ++r)
          Ps[(prow + r) * LDP + j * 16 + r16] = __float2bfloat16(sc[j][r]);
    }
    __syncthreads();

    // O += P @ V via VT[d][key]
    #pragma unroll
    for (int kk = 0; kk < 2; ++kk) {
      bf16x8 af_p, bv_f[4];
      af_p = *(const bf16x8*)&Ps[(wq0 + r16) * LDP + kk * 32 + quad * 8];
      #pragma unroll
      for (int jd = 0; jd < 4; ++jd)
        bv_f[jd] = *(const bf16x8*)&VTs[(jd * 16 + r16) * LDP + kk * 32 + quad * 8];
      #pragma unroll
      for (int jd = 0; jd < 4; ++jd)
        O[jd] = __builtin_amdgcn_mfma_f32_16x16x32_bf16(af_p, bv_f[jd], O[jd], 0, 0, 0);
    }
  }

  // epilogue: unnormalized fp32 O + (m,l)
  float* Ob = Osp + (long)split * SEQ * 1024;
  #pragma unroll
  for (int r = 0; r < 4; ++r) {
    long row = s0 + wq0 + quad * 4 + r;
    #pragma unroll
    for (int jd = 0; jd < 4; ++jd)
      Ob[row * 1024 + h * 64 + jd * 16 + r16] = O[jd][r];
    if (r16 == 0)
      ml[((long)(split * 16 + h)) * SEQ + row] = make_float2(m_s[r], l_s[r]);
  }
}

// merge the two key-splits -> ctx bf16
__global__ __launch_bounds__(256) void attn_combine(
    const float* __restrict__ Osp, const float2* __restrict__ ml,
    bf16* __restrict__ ctx)
{
  constexpr long SD = 2048L * 1024L;
  const int s = blockIdx.x;
  const int t = threadIdx.x;
  #pragma unroll
  for (int i = 0; i < 4; ++i) {
    int c = t + i * 256;
    int h = c >> 6;
    float2 a = ml[(long)h * 2048 + s];
    float2 b = ml[(long)(16 + h) * 2048 + s];
    float mC = fmaxf(a.x, b.x);
    float w0 = exp2f(a.x - mC), w1 = exp2f(b.x - mC);
    float inv = 1.f / (a.y * w0 + b.y * w1);
    float o = (Osp[(long)s * 1024 + c] * w0 + Osp[SD + (long)s * 1024 + c] * w1) * inv;
    ctx[(long)s * 1024 + c] = __float2bfloat16(o);
  }
}

// fp32 weight [R][C] -> bf16 transposed [C][R]
__global__ __launch_bounds__(256) void transpose_cast(
    const float* __restrict__ in, bf16* __restrict__ out, int R, int C)
{
  __shared__ bf16 tile[32][33];
  const int tx = threadIdx.x, ty = threadIdx.y;
  const int r0 = blockIdx.y * 32, c0 = blockIdx.x * 32;
  #pragma unroll
  for (int d = 0; d < 32; d += 8)
    tile[ty + d][tx] = __float2bfloat16(in[(long)(r0 + ty + d) * C + c0 + tx]);
  __syncthreads();
  #pragma unroll
  for (int d = 0; d < 32; d += 8)
    out[(long)(c0 + ty + d) * R + r0 + tx] = tile[tx][ty + d];
}

// bf16 [R][C] (row stride ldin) -> bf16 transposed [C][R]
__global__ __launch_bounds__(256) void transpose_bf16(
    const bf16* __restrict__ in, bf16* __restrict__ out, int R, int C, int ldin)
{
  __shared__ bf16 tile[32][33];
  const int tx = threadIdx.x, ty = threadIdx.y;
  const int r0 = blockIdx.y * 32, c0 = blockIdx.x * 32;
  #pragma unroll
  for (int d = 0; d < 32; d += 8)
    tile[ty + d][tx] = in[(long)(r0 + ty + d) * ldin + c0 + tx];
  __syncthreads();
  #pragma unroll
  for (int d = 0; d < 32; d += 8)
    out[(long)(c0 + ty + d) * R + r0 + tx] = tile[tx][ty + d];
}

__device__ __forceinline__ float blk_sum(float v, float* sh) {
  #pragma unroll
  for (int o = 32; o > 0; o >>= 1) v += __shfl_down(v, o);
  __syncthreads();
  if ((threadIdx.x & 63) == 0) sh[threadIdx.x >> 6] = v;
  __syncthreads();
  return sh[0] + sh[1] + sh[2] + sh[3];
}

// X = LN(X + d0 + d1 + bias)*g + b, writes bf16 copy to xb.
__global__ __launch_bounds__(256) void ln_residual2(
    float* __restrict__ X, const float* __restrict__ d0, const float* __restrict__ d1,
    const float* __restrict__ bias,
    const float* __restrict__ g, const float* __restrict__ b,
    bf16* __restrict__ xb)
{
  __shared__ float sh[4];
  const int t = threadIdx.x;
  const long base = (long)blockIdx.x * 1024;
  float v[4]; float s = 0.f;
  #pragma unroll
  for (int i = 0; i < 4; ++i) {
    int c = t + i * 256;
    float val = X[base + c] + d0[base + c] + d1[base + c] + bias[c];
    v[i] = val; s += val;
  }
  s = blk_sum(s, sh);
  const float mu = s * (1.f / 1024.f);
  float s2 = 0.f;
  #pragma unroll
  for (int i = 0; i < 4; ++i) { float d = v[i] - mu; s2 += d * d; }
  s2 = blk_sum(s2, sh);
  const float rs = rsqrtf(s2 * (1.f / 1024.f) + 1e-5f);
  #pragma unroll
  for (int i = 0; i < 4; ++i) {
    int c = t + i * 256;
    float o = (v[i] - mu) * rs * g[c] + b[c];
    X[base + c] = o;
    xb[base + c] = __float2bfloat16(o);
  }
}

__global__ __launch_bounds__(256) void init_x(
    const float* __restrict__ xin, float* __restrict__ X, bf16* __restrict__ xb, int n)
{
  for (int i = blockIdx.x * 256 + threadIdx.x; i < n; i += gridDim.x * 256) {
    float v = xin[i];
    X[i] = v;
    xb[i] = __float2bfloat16(v);
  }
}

__global__ __launch_bounds__(256) void copy_out(
    const float* __restrict__ X, float* __restrict__ out, int n)
{
  for (int i = blockIdx.x * 256 + threadIdx.x; i < n; i += gridDim.x * 256)
    out[i] = X[i];
}

// bias3[l][j][c] = {bq,bk,bv}[l][c]
__global__ __launch_bounds__(256) void concat_bias(
    const float* __restrict__ bq, const float* __restrict__ bk,
    const float* __restrict__ bv, float* __restrict__ out, int n)
{
  for (int i = blockIdx.x * 256 + threadIdx.x; i < n; i += gridDim.x * 256) {
    int l = i / 3072, r = i % 3072;
    int j = r / 1024, c = r % 1024;
    const float* src = (j == 0) ? bq : (j == 1) ? bk : bv;
    out[i] = src[l * 1024 + c];
  }
}

extern "C" void kernel_launch(void* const* d_in, const int* in_sizes, int n_in,
                              void* d_out, int out_size, void* d_ws, size_t ws_size,
                              hipStream_t stream) {
  constexpr int S = 2048, D = 1024, F = 4096, L = 4;
  const float* xin = (const float*)d_in[0];
  const float* wq = (const float*)d_in[1];
  const float* bq = (const float*)d_in[2];
  const float* wk = (const float*)d_in[3];
  const float* bk = (const float*)d_in[4];
  const float* wv = (const float*)d_in[5];
  const float* bvp = (const float*)d_in[6];
  const float* wo = (const float*)d_in[7];
  const float* bo = (const float*)d_in[8];
  const float* w1 = (const float*)d_in[9];
  const float* b1 = (const float*)d_in[10];
  const float* w2 = (const float*)d_in[11];
  const float* b2 = (const float*)d_in[12];
  const float* ln1g = (const float*)d_in[13];
  const float* ln1b = (const float*)d_in[14];
  const float* ln2g = (const float*)d_in[15];
  const float* ln2b = (const float*)d_in[16];

  // workspace ~58 MB. tmpf doubles as flash O-split slabs; hb overlays qkv..ctx.
  char* p = (char*)d_ws;
  float* X    = (float*)p; p += (long)S * D * 4;        // 8 MB
  float* tmpf = (float*)p; p += 2L * S * D * 4;         // 16 MB (split-K / O-split slabs)
  bf16* xb    = (bf16*)p;  p += (long)S * D * 2;        // 4 MB
  bf16* qkv   = (bf16*)p;                               // 12 MB
  bf16* hb    = (bf16*)p;  p += (long)S * 3 * D * 2;    // hb overlays qkv..ctx
  bf16* ctx   = (bf16*)p;  p += (long)S * D * 2;        // 4 MB
  bf16* vT    = (bf16*)p;  p += (long)S * D * 2;        // 4 MB  [H*64][S]
  bf16* wT    = (bf16*)p;  p += (long)F * D * 2;        // 8 MB
  float* bias3= (float*)p; p += (long)L * 3 * D * 4;    // 48 KB
  float2* ml  = (float2*)p; p += 2L * 16 * S * 8;       // 512 KB (m,l per split/head/row)

  init_x<<<2048, 256, 0, stream>>>(xin, X, xb, S * D);
  concat_bias<<<48, 256, 0, stream>>>(bq, bk, bvp, bias3, L * 3 * D);

  for (int l = 0; l < L; ++l) {
    // fused QKV
    transpose_cast<<<dim3(D / 32, D / 32), dim3(32, 8), 0, stream>>>(wq + (long)l * D * D, wT, D, D);
    transpose_cast<<<dim3(D / 32, D / 32), dim3(32, 8), 0, stream>>>(wk + (long)l * D * D, wT + (long)D * D, D, D);
    transpose_cast<<<dim3(D / 32, D / 32), dim3(32, 8), 0, stream>>>(wv + (long)l * D * D, wT + 2L * D * D, D, D);
    gemm_bt<128, 128, 64, EPI_BIAS_BF16, bf16><<<dim3(3 * D / 128, S / 128, 1), 256, 0, stream>>>(
        xb, 0L, D, wT, 0L, D, qkv, 0L, 3 * D, bias3 + l * 3 * D, D, 1.f);

    // vT[h*64+d][s]
    transpose_bf16<<<dim3(D / 32, S / 32), dim3(32, 8), 0, stream>>>(qkv + 2 * D, vT, S, D, 3 * D);

    // key-split flash + combine
    flash_attn<<<dim3(S / 64, 16, 2), 256, 0, stream>>>(qkv, vT, tmpf, ml);
    attn_combine<<<S, 256, 0, stream>>>(tmpf, ml, ctx);

    // attn-out, split-K 2 -> fp32 slabs
    transpose_cast<<<dim3(D / 32, D / 32), dim3(32, 8), 0, stream>>>(wo + (long)l * D * D, wT, D, D);
    gemm_bt<128, 64, 64, EPI_NONE, float><<<dim3(D / 64, S / 128, 2), 256, 0, stream>>>(
        ctx, (long)(D / 2), D, wT, (long)(D / 2), D, tmpf, (long)S * D, D, nullptr, D / 2, 1.f);
    ln_residual2<<<S, 256, 0, stream>>>(X, tmpf, tmpf + (long)S * D, bo + l * D,
                                        ln1g + l * D, ln1b + l * D, xb);

    // FFN
    transpose_cast<<<dim3(F / 32, D / 32), dim3(32, 8), 0, stream>>>(w1 + (long)l * D * F, wT, D, F);
    gemm_bt<128, 128, 64, EPI_BIAS_GELU_BF16, bf16><<<dim3(F / 128, S / 128, 1), 256, 0, stream>>>(
        xb, 0L, D, wT, 0L, D, hb, 0L, F, b1 + l * F, D, 1.f);
    transpose_cast<<<dim3(D / 32, F / 32), dim3(32, 8), 0, stream>>>(w2 + (long)l * F * D, wT, F, D);
    gemm_bt<128, 64, 64, EPI_NONE, float><<<dim3(D / 64, S / 128, 2), 256, 0, stream>>>(
        hb, (long)(F / 2), F, wT, (long)(F / 2), F, tmpf, (long)S * D, D, nullptr, F / 2, 1.f);
    ln_residual2<<<S, 256, 0, stream>>>(X, tmpf, tmpf + (long)S * D, b2 + l * D,
                                        ln2g + l * D, ln2b + l * D, xb);
  }
  copy_out<<<2048, 256, 0, stream>>>(X, (float*)d_out, S * D);
}